// Round 19
// baseline (333.240 us; speedup 1.0000x reference)
//
#include <hip/hip_runtime.h>
#include <hip/hip_bf16.h>

typedef unsigned short ushort_t;
typedef __attribute__((ext_vector_type(8))) short bf16x8;
typedef __attribute__((ext_vector_type(4))) float f32x4;

// ---------------- constants ----------------
#define N_AC 40000
#define N_W  20000
#define D_IN 128
#define NH   4
#define HD   256
#define DOUT 64
#define E_TIC 400000
#define E_W   200000
#define E_REL 400000
#define E_ALL 1000000
#define N_ALL 80000
#define NEG 0.2f
#define CAP 96
#define FCH 4096
#define ELLW 64

__device__ __forceinline__ float bf2f(ushort_t u) {
    return __uint_as_float(((unsigned int)u) << 16);
}
__device__ __forceinline__ ushort_t f2bf(float v) {
    unsigned u = __float_as_uint(v);
    unsigned r = (u + 0x7fffu + ((u >> 16) & 1u)) >> 16;
    return (ushort_t)r;
}
__device__ __forceinline__ float ldf(const void* p, size_t i, int f) {
    return f ? ((const float*)p)[i] : bf2f(((const ushort_t*)p)[i]);
}
__device__ __forceinline__ float lrelu_exp(float v) {
    v = v > 0.f ? v : NEG * v;
    return __expf(v);
}

// ---------------- dtype autodetect ----------------
__global__ void detect_dtype(const ushort_t* __restrict__ x, int* __restrict__ flag) {
    __shared__ int hit;
    if (threadIdx.x == 0) hit = 0;
    __syncthreads();
    for (int i = threadIdx.x; i < 4096; i += 256) {
        float v = bf2f(x[i]);
        if (!(fabsf(v) <= 1e4f)) atomicOr(&hit, 1);
    }
    __syncthreads();
    if (threadIdx.x == 0) flag[0] = hit ? 1 : 0;
}

// ---------------- canonicalize 24 small param tensors to f32 ----------------
struct CvtTab { const void* src[24]; int n[24]; int off[24]; };
__global__ __launch_bounds__(256) void cvt_inputs(CvtTab t, float* __restrict__ par,
                                                  const int* __restrict__ flagp) {
    int ent = blockIdx.x >> 3, sub = blockIdx.x & 7;
    int f = flagp[0];
    const void* s = t.src[ent];
    int n = t.n[ent];
    float* d = par + t.off[ent];
    for (int i = sub * 256 + threadIdx.x; i < n; i += 8 * 256)
        d[i] = f ? ((const float*)s)[i] : bf2f(((const ushort_t*)s)[i]);
}

// ---------------- q vectors (rel-dst cases only) ----------------
struct QTab { int woff[2]; int aoff[2]; int qoff[2]; int K[2]; int Hh[2]; };
__global__ __launch_bounds__(256) void make_q(QTab t, float* __restrict__ par) {
    int b = blockIdx.x;
    int k = threadIdx.x;
    int K = t.K[b], Hh = t.Hh[b];
    if (k >= K) return;
    const float* W = par + t.woff[b];
    const float* a = par + t.aoff[b];
    float* q = par + t.qoff[b];
    int HDc = Hh * 64;
    for (int h = 0; h < Hh; ++h) {
        float s = 0.f;
        for (int d = 0; d < 64; ++d) s += W[(size_t)k * HDc + h * 64 + d] * a[h * 64 + d];
        q[k * Hh + h] = s;
    }
}

// ---------------- pack W^T to bf16 (N x K row-major) ----------------
struct PTab { int woff[6]; int toff[6]; int Klog[6]; int N[6]; };
__global__ __launch_bounds__(256) void pack_wt(PTab t, const float* __restrict__ par,
                                               ushort_t* __restrict__ wt) {
    int m = blockIdx.x >> 4, sub = blockIdx.x & 15;
    int Klog = t.Klog[m], K = 1 << Klog, Nn = t.N[m];
    int tot = K * Nn;
    const float* Wp = par + t.woff[m];
    ushort_t* d = wt + t.toff[m];
    for (int i = sub * 256 + threadIdx.x; i < tot; i += 16 * 256) {
        int n = i >> Klog, k = i & (K - 1);
        d[i] = f2bf(Wp[(size_t)k * Nn + n]);
    }
}

// ================= device bodies =========

__device__ __forceinline__ void dev_mgemm1(int b, const void* X, int f,
                                           const ushort_t* WT, ushort_t* Zb,
                                           const float* alp, const float* arp,
                                           float* elo, float* ero) {
    const int w = threadIdx.x >> 6, l = threadIdx.x & 63;
    const int row0 = b * 16;
    const int lr = l & 15, lk = l >> 4;

    bf16x8 a[4];
    if (!f) {
        const ushort_t* xp = (const ushort_t*)X + (size_t)(row0 + lr) * 128 + lk * 8;
        #pragma unroll
        for (int ks = 0; ks < 4; ++ks) a[ks] = *(const bf16x8*)(xp + ks * 32);
    } else {
        const float* xp = (const float*)X + (size_t)(row0 + lr) * 128 + lk * 8;
        #pragma unroll
        for (int ks = 0; ks < 4; ++ks)
            #pragma unroll
            for (int j = 0; j < 8; ++j) a[ks][j] = (short)f2bf(xp[ks * 32 + j]);
    }

    f32x4 acc[4] = {{0.f,0.f,0.f,0.f},{0.f,0.f,0.f,0.f},{0.f,0.f,0.f,0.f},{0.f,0.f,0.f,0.f}};
    const int col0 = w * 64;
    #pragma unroll
    for (int ks = 0; ks < 4; ++ks) {
        #pragma unroll
        for (int nt = 0; nt < 4; ++nt) {
            bf16x8 bb = *(const bf16x8*)(WT + (size_t)(col0 + nt * 16 + lr) * 128 + ks * 32 + lk * 8);
            acc[nt] = __builtin_amdgcn_mfma_f32_16x16x32_bf16(a[ks], bb, acc[nt], 0, 0, 0);
        }
    }
    #pragma unroll
    for (int nt = 0; nt < 4; ++nt)
        #pragma unroll
        for (int r = 0; r < 4; ++r)
            Zb[(size_t)(row0 + lk * 4 + r) * HD + col0 + nt * 16 + lr] = f2bf(acc[nt][r]);

    if (alp) {
        float a0 = alp[col0 + lr], a1 = alp[col0 + 16 + lr],
              a2 = alp[col0 + 32 + lr], a3 = alp[col0 + 48 + lr];
        #pragma unroll
        for (int r = 0; r < 4; ++r) {
            float v = acc[0][r] * a0 + acc[1][r] * a1 + acc[2][r] * a2 + acc[3][r] * a3;
            v += __shfl_xor(v, 1, 64); v += __shfl_xor(v, 2, 64);
            v += __shfl_xor(v, 4, 64); v += __shfl_xor(v, 8, 64);
            if (lr == r) elo[(size_t)(row0 + lk * 4 + r) * 4 + w] = v;
        }
    }
    if (arp) {
        float a0 = arp[col0 + lr], a1 = arp[col0 + 16 + lr],
              a2 = arp[col0 + 32 + lr], a3 = arp[col0 + 48 + lr];
        #pragma unroll
        for (int r = 0; r < 4; ++r) {
            float v = acc[0][r] * a0 + acc[1][r] * a1 + acc[2][r] * a2 + acc[3][r] * a3;
            v += __shfl_xor(v, 1, 64); v += __shfl_xor(v, 2, 64);
            v += __shfl_xor(v, 4, 64); v += __shfl_xor(v, 8, 64);
            if (lr == r) ero[(size_t)(row0 + lk * 4 + r) * 4 + w] = v;
        }
    }
}

// class-partitioned ELL fill with etype-aware edge ranges (round-18 form).
__device__ __forceinline__ void dev_fill_ell(int b,
        const int* s0, const int* d0, const void* w0,
        const int* s1, const int* d1, const void* w1,
        const int* s2, const int* d2, const void* w2,
        int f, int* cnt, unsigned* adj) {
    const int CB[9]  = {0, 12500, 25000, 37500, 50000, 61250, 67500, 73750, 80000};
    const int F[9]   = {0, 98, 196, 294, 441, 589, 688, 787, 886};
    const int CLO[8] = {0, 0, 0, 0, 97, 146, 146, 146};
    const int ELO[8] = {0, 0, 0, 0, E_TIC, E_TIC + E_W, E_TIC + E_W, E_TIC + E_W};
    const int EHI[8] = {E_TIC, E_TIC, E_TIC, E_TIC + E_W, E_ALL, E_ALL, E_ALL, E_ALL};
    int cls = 0;
    while (b >= F[cls + 1]) ++cls;          // b < 886, uniform
    const int lo = CB[cls], hi = CB[cls + 1];
    const int eLo = ELO[cls], eHi = EHI[cls];
    const int e0 = (CLO[cls] + (b - F[cls])) * FCH;
    for (int i = threadIdx.x; i < FCH; i += 256) {
        int e = e0 + i;
        if (e < eLo || e >= eHi) continue;
        int g;
        if (e < E_TIC) g = d0[e];
        else if (e < E_TIC + E_W) g = N_AC + d1[e - E_TIC];
        else g = N_AC + N_W + d2[e - E_TIC - E_W];
        if (g < lo || g >= hi) continue;
        int sn; float ew;
        if (e < E_TIC) { sn = s0[e]; ew = ldf(w0, e, f); }
        else if (e < E_TIC + E_W) { int le = e - E_TIC; sn = s1[le]; ew = ldf(w1, le, f); }
        else { int le = e - E_TIC - E_W; sn = s2[le]; ew = ldf(w2, le, f); }
        int r = atomicAdd(&cnt[g], 1);
        if (r < ELLW)
            adj[(size_t)g * ELLW + r] = (unsigned)(sn & 0xFFFF) | ((unsigned)f2bf(ew) << 16);
    }
}
#define FILL_BLOCKS 886

__device__ __forceinline__ void dev_elr1(int b, const void* X, int f,
                                         const float* q0, float* o0,
                                         int N, int D, int Hh) {
    __shared__ float qs[512];
    const int tid = threadIdx.x;
    const int tot = D * Hh;
    for (int i = tid; i < tot; i += 256) {
        int k, h;
        if (Hh == 4) { k = i >> 2; h = i & 3; } else { k = i; h = 0; }
        qs[h * D + k] = q0[i];
    }
    __syncthreads();
    const int wid = tid >> 6, lane = tid & 63;
    const int n = b * 4 + wid;
    if (n >= N) return;
    const int J = D >> 6;
    float x[4];
    for (int j = 0; j < J; ++j) x[j] = ldf(X, (size_t)n * D + j * 64 + lane, f);
    for (int h = 0; h < Hh; ++h) {
        float v = 0.f;
        for (int j = 0; j < J; ++j) v += x[j] * qs[h * D + j * 64 + lane];
        #pragma unroll
        for (int o = 32; o > 0; o >>= 1) v += __shfl_down(v, o, 64);
        if (lane == 0) o0[n * Hh + h] = v;
    }
}

// gat1 body (ELL or CSR); MODE 2 optionally computes e2out[n] = h_word . q2
template <int MODE>
__device__ __forceinline__ void dev_gat1(int b,
        const int* rp, const int* degp, int gbase, int ell,
        const unsigned* adj, const ushort_t* zb,
        const float* el, const float* er, const float* bias,
        ushort_t* H, int N, const float* q2, float* e2out) {
    __shared__ float atl[4][CAP * 4];
    __shared__ int   snl[4][CAP];
    const int w = threadIdx.x >> 6, lane = threadIdx.x & 63;
    const int n = b * 4 + w;
    if (n >= N) return;
    const int h = lane >> 4;
    int beg, deg;
    if (ell) {
        int g = gbase + n;
        beg = g * ELLW;
        deg = degp[g];
        deg = deg < ELLW ? deg : ELLW;
    } else {
        beg = rp[n];
        deg = rp[n + 1] - beg;
    }
    const float4* el4 = (const float4*)el;
    const float4 ern = ((const float4*)er)[n];

    float4 ss = make_float4(0.f, 0.f, 0.f, 0.f);
    for (int base = 0; base < deg; base += 64) {
        int i = base + lane;
        if (i < deg) {
            unsigned ae = adj[beg + i];
            int sn = ae & 0xFFFF;
            float4 e = el4[sn];
            float x0 = lrelu_exp(e.x + ern.x);
            float x1 = lrelu_exp(e.y + ern.y);
            float x2 = lrelu_exp(e.z + ern.z);
            float x3 = lrelu_exp(e.w + ern.w);
            ss.x += x0; ss.y += x1; ss.z += x2; ss.w += x3;
            if (i < CAP) {
                float ew = bf2f((ushort_t)(ae >> 16));
                float4* dst4 = (float4*)&atl[w][i * 4];
                *dst4 = make_float4(x0 * ew, x1 * ew, x2 * ew, x3 * ew);
                snl[w][i] = sn;
            }
        }
    }
    #pragma unroll
    for (int o = 32; o > 0; o >>= 1) {
        ss.x += __shfl_xor(ss.x, o, 64);
        ss.y += __shfl_xor(ss.y, o, 64);
        ss.z += __shfl_xor(ss.z, o, 64);
        ss.w += __shfl_xor(ss.w, o, 64);
    }
    const float sh = (h == 0) ? ss.x : (h == 1) ? ss.y : (h == 2) ? ss.z : ss.w;
    const float inv = 1.f / (sh + 1e-9f);
    const float erh = (h == 0) ? ern.x : (h == 1) ? ern.y : (h == 2) ? ern.z : ern.w;

    float a0 = 0.f, a1 = 0.f, a2 = 0.f, a3 = 0.f;
    #pragma unroll 4
    for (int i = 0; i < deg; ++i) {
        int sn; float atv;
        if (i < CAP) {
            sn = snl[w][i];
            atv = atl[w][i * 4 + h];
        } else {
            unsigned ae = adj[beg + i];
            sn = ae & 0xFFFF;
            atv = lrelu_exp(el[sn * 4 + h] + erh) * bf2f((ushort_t)(ae >> 16));
        }
        ushort4 zv = *(const ushort4*)(zb + (size_t)sn * HD + lane * 4);
        a0 += bf2f(zv.x) * atv; a1 += bf2f(zv.y) * atv;
        a2 += bf2f(zv.z) * atv; a3 += bf2f(zv.w) * atv;
    }
    float4 bb = *(const float4*)(bias + lane * 4);
    a0 = a0 * inv + bb.x; a1 = a1 * inv + bb.y;
    a2 = a2 * inv + bb.z; a3 = a3 * inv + bb.w;

    ushort_t* hp = H + (size_t)n * HD + lane * 4;
    ushort4 o;
    if (MODE == 0) {
        o.x = f2bf(a0 > 0.f ? a0 : 0.f); o.y = f2bf(a1 > 0.f ? a1 : 0.f);
        o.z = f2bf(a2 > 0.f ? a2 : 0.f); o.w = f2bf(a3 > 0.f ? a3 : 0.f);
    } else if (MODE == 1) {
        o.x = f2bf(a0 > 0.f ? a0 : expm1f(a0)); o.y = f2bf(a1 > 0.f ? a1 : expm1f(a1));
        o.z = f2bf(a2 > 0.f ? a2 : expm1f(a2)); o.w = f2bf(a3 > 0.f ? a3 : expm1f(a3));
    } else {
        ushort4 hw = *(const ushort4*)hp;
        float v0 = (bf2f(hw.x) + (a0 > 0.f ? a0 : expm1f(a0))) * 0.5f;
        float v1 = (bf2f(hw.y) + (a1 > 0.f ? a1 : expm1f(a1))) * 0.5f;
        float v2 = (bf2f(hw.z) + (a2 > 0.f ? a2 : expm1f(a2))) * 0.5f;
        float v3 = (bf2f(hw.w) + (a3 > 0.f ? a3 : expm1f(a3))) * 0.5f;
        v0 = v0 > 0.f ? v0 : 0.f; v1 = v1 > 0.f ? v1 : 0.f;
        v2 = v2 > 0.f ? v2 : 0.f; v3 = v3 > 0.f ? v3 : 0.f;
        o.x = f2bf(v0); o.y = f2bf(v1); o.z = f2bf(v2); o.w = f2bf(v3);
        if (q2) {   // fused E2rr = h_word . q2
            const int c4 = lane * 4;
            float d = v0 * q2[c4] + v1 * q2[c4 + 1] + v2 * q2[c4 + 2] + v3 * q2[c4 + 3];
            #pragma unroll
            for (int oo = 32; oo > 0; oo >>= 1) d += __shfl_xor(d, oo, 64);
            if (lane == 0) e2out[n] = d;
        }
    }
    *(ushort4*)hp = o;
}

// ================= fused front-end (path A): MFMA first, fill LAST =========
// Blocks dispatch roughly in ascending order; placing the atomic-heavy fill
// at the END lets the 3250 MFMA blocks saturate CUs and retire at full speed,
// after which the fill's atomic stream runs mostly solo at its 23 G/s rate
// (vs 12 G/s when concurrent -- round-15/18 measurements).
struct FA {
    const int *s0, *d0; const void* w0;
    const int *s1, *d1; const void* w1;
    const int *s2, *d2; const void* w2;
    const int* flagp; int* cnt; unsigned* adj;
    const void* x_ac; const void* x_w;
    const ushort_t *WTt, *WTw, *WTr;
    ushort_t *Zt, *Zw, *Zr;
    const float *al1t, *ar1t, *al1w, *ar1w, *al1r;
    float *ELt, *ERt, *ELw, *ERw, *ELr, *ERr;
    const float* qer1r;
    unsigned c0, c1, c2, c3;
};
__global__ __launch_bounds__(256) void fused_a(FA a) {
    const unsigned b = blockIdx.x;
    const int f = a.flagp[0];
    if (b < a.c0) {
        dev_mgemm1(b, a.x_ac, f, a.WTt, a.Zt, a.al1t, a.ar1t, a.ELt, a.ERt);
    } else if (b < a.c1) {
        dev_mgemm1(b - a.c0, a.x_w, f, a.WTw, a.Zw, a.al1w, a.ar1w, a.ELw, a.ERw);
    } else if (b < a.c2) {
        dev_mgemm1(b - a.c1, a.x_ac, f, a.WTr, a.Zr, a.al1r, nullptr, a.ELr, nullptr);
    } else if (b < a.c3) {
        dev_elr1(b - a.c2, a.x_w, f, a.qer1r, a.ERr, N_W, 128, 4);
    } else {
        dev_fill_ell(b - a.c3, a.s0, a.d0, a.w0, a.s1, a.d1, a.w1, a.s2, a.d2, a.w2,
                     f, a.cnt, a.adj);
    }
}

// fused gat1 tic+w (ELL mode)
struct GT {
    const int* degp; const unsigned* adj;
    const ushort_t *Zt, *Zw;
    const float *ELt, *ERt, *ELw, *ERw, *b1t, *b1w;
    ushort_t *Hac, *Hw;
    unsigned b1;
};
__global__ __launch_bounds__(256) void gat1_tw(GT t) {
    if (blockIdx.x < t.b1)
        dev_gat1<0>(blockIdx.x, nullptr, t.degp, 0, 1, t.adj, t.Zt,
                    t.ELt, t.ERt, t.b1t, t.Hac, N_AC, nullptr, nullptr);
    else
        dev_gat1<1>(blockIdx.x - t.b1, nullptr, t.degp, N_AC, 1, t.adj, t.Zw,
                    t.ELw, t.ERw, t.b1w, t.Hw, N_W, nullptr, nullptr);
}

// standalone gat1 wrapper (path B + path A rel)
template <int MODE>
__global__ __launch_bounds__(256) void gat1(const int* __restrict__ rp,
                                            const int* __restrict__ degp,
                                            int gbase, int ell,
                                            const unsigned* __restrict__ adj,
                                            const ushort_t* __restrict__ zb,
                                            const float* __restrict__ el,
                                            const float* __restrict__ er,
                                            const float* __restrict__ bias,
                                            ushort_t* __restrict__ H, int N,
                                            const float* __restrict__ q2,
                                            float* __restrict__ e2out) {
    dev_gat1<MODE>(blockIdx.x, rp, degp, gbase, ell, adj, zb, el, er, bias, H, N, q2, e2out);
}

// ================= path-B CSR build (round-12 proven form) =================
__global__ __launch_bounds__(256) void count3(const int* __restrict__ d0,
                                              const int* __restrict__ d1,
                                              const int* __restrict__ d2,
                                              int* __restrict__ cnt,
                                              int* __restrict__ rank) {
    int e = blockIdx.x * 256 + threadIdx.x;
    if (e >= E_ALL) return;
    int g;
    if (e < E_TIC) g = d0[e];
    else if (e < E_TIC + E_W) g = N_AC + d1[e - E_TIC];
    else g = N_AC + N_W + d2[e - E_TIC - E_W];
    rank[e] = atomicAdd(&cnt[g], 1);
}

__global__ __launch_bounds__(256) void scan_bsum(const int* __restrict__ cnt,
                                                 int* __restrict__ bsum, int N) {
    __shared__ int red[256];
    int i = blockIdx.x * 256 + threadIdx.x;
    red[threadIdx.x] = (i < N) ? cnt[i] : 0;
    __syncthreads();
    #pragma unroll
    for (int o = 128; o > 0; o >>= 1) {
        if (threadIdx.x < o) red[threadIdx.x] += red[threadIdx.x + o];
        __syncthreads();
    }
    if (threadIdx.x == 0) bsum[blockIdx.x] = red[0];
}

__global__ __launch_bounds__(512) void scan_top(int* __restrict__ bsum, int B) {
    __shared__ int sc[512];
    const int t = threadIdx.x;
    int v = (t < B) ? bsum[t] : 0;
    sc[t] = v;
    __syncthreads();
    #pragma unroll
    for (int o = 1; o < 512; o <<= 1) {
        int u = (t >= o) ? sc[t - o] : 0;
        __syncthreads();
        sc[t] += u;
        __syncthreads();
    }
    if (t < B) bsum[t] = sc[t] - v;
}

__global__ __launch_bounds__(256) void scan_out(const int* __restrict__ cnt,
                                                const int* __restrict__ bsum,
                                                int* __restrict__ rowptr, int N) {
    __shared__ int sc[256];
    const int t = threadIdx.x;
    int i = blockIdx.x * 256 + t;
    int v = (i < N) ? cnt[i] : 0;
    sc[t] = v;
    __syncthreads();
    #pragma unroll
    for (int o = 1; o < 256; o <<= 1) {
        int u = (t >= o) ? sc[t - o] : 0;
        __syncthreads();
        sc[t] += u;
        __syncthreads();
    }
    int ex = sc[t] - v + bsum[blockIdx.x];
    if (i < N) {
        rowptr[i] = ex;
        if (i == N - 1) rowptr[N] = ex + v;
    }
}

__global__ __launch_bounds__(256) void fill3(const int* __restrict__ s0, const int* __restrict__ d0, const void* __restrict__ w0,
                                             const int* __restrict__ s1, const int* __restrict__ d1, const void* __restrict__ w1,
                                             const int* __restrict__ s2, const int* __restrict__ d2, const void* __restrict__ w2,
                                             const int* __restrict__ flagp,
                                             const int* __restrict__ rp,
                                             const int* __restrict__ rank,
                                             unsigned* __restrict__ adj) {
    const int CB[9] = {0, 12500, 25000, 37500, 50000, 61250, 67500, 73750, 80000};
    const int cls = blockIdx.x & 7;
    const int lo = CB[cls], hi = CB[cls + 1];
    const int f = flagp[0];
    const int e0 = (blockIdx.x >> 3) * FCH;
    for (int i = threadIdx.x; i < FCH; i += 256) {
        int e = e0 + i;
        if (e >= E_ALL) return;
        int g;
        if (e < E_TIC) g = d0[e];
        else if (e < E_TIC + E_W) g = N_AC + d1[e - E_TIC];
        else g = N_AC + N_W + d2[e - E_TIC - E_W];
        if (g < lo || g >= hi) continue;
        int sn; float ew;
        if (e < E_TIC) { sn = s0[e]; ew = ldf(w0, e, f); }
        else if (e < E_TIC + E_W) { int le = e - E_TIC; sn = s1[le]; ew = ldf(w1, le, f); }
        else { int le = e - E_TIC - E_W; sn = s2[le]; ew = ldf(w2, le, f); }
        int pos = rp[g] + rank[e];
        adj[pos] = (unsigned)(sn & 0xFFFF) | ((unsigned)f2bf(ew) << 16);
    }
}

// ---------------- standalone wrappers ----------------
__global__ __launch_bounds__(256) void mgemm1(const void* __restrict__ X,
                                              const int* __restrict__ flagp,
                                              const ushort_t* __restrict__ WT,
                                              ushort_t* __restrict__ Zb,
                                              const float* __restrict__ alp,
                                              const float* __restrict__ arp,
                                              float* __restrict__ elo,
                                              float* __restrict__ ero) {
    dev_mgemm1(blockIdx.x, X, flagp[0], WT, Zb, alp, arp, elo, ero);
}

__global__ __launch_bounds__(256) void elr1(const void* __restrict__ X,
                                            const int* __restrict__ flagp,
                                            const float* __restrict__ q0,
                                            float* __restrict__ o0,
                                            int N, int D, int Hh) {
    dev_elr1(blockIdx.x, X, flagp ? flagp[0] : 0, q0, o0, N, D, Hh);
}

// ---------------- MFMA GEMM L2 fused over 3 etype segments ----------------
struct G2 {
    const ushort_t* Hb[3]; const ushort_t* WT[3]; ushort_t* Zc[3];
    const float* al[3]; const float* ar[3]; float* el[3]; float* er[3];
    int N[3]; int b1, b2;
};
__global__ __launch_bounds__(256) void mgemm2_all(G2 t) {
    int s, b;
    if (blockIdx.x < (unsigned)t.b1) { s = 0; b = blockIdx.x; }
    else if (blockIdx.x < (unsigned)t.b2) { s = 1; b = blockIdx.x - t.b1; }
    else { s = 2; b = blockIdx.x - t.b2; }
    const int w = threadIdx.x >> 6, l = threadIdx.x & 63;
    const int row0 = b * 64 + w * 16;
    if (row0 >= t.N[s]) return;
    const int lr = l & 15, lk = l >> 4;
    const ushort_t* ap = t.Hb[s] + (size_t)(row0 + lr) * 256 + lk * 8;
    const ushort_t* WT = t.WT[s];

    f32x4 acc[4] = {{0.f,0.f,0.f,0.f},{0.f,0.f,0.f,0.f},{0.f,0.f,0.f,0.f},{0.f,0.f,0.f,0.f}};
    #pragma unroll
    for (int ks = 0; ks < 8; ++ks) {
        bf16x8 a = *(const bf16x8*)(ap + ks * 32);
        #pragma unroll
        for (int nt = 0; nt < 4; ++nt) {
            bf16x8 bb = *(const bf16x8*)(WT + (size_t)(nt * 16 + lr) * 256 + ks * 32 + lk * 8);
            acc[nt] = __builtin_amdgcn_mfma_f32_16x16x32_bf16(a, bb, acc[nt], 0, 0, 0);
        }
    }
    ushort_t* Zc = t.Zc[s];
    #pragma unroll
    for (int nt = 0; nt < 4; ++nt)
        #pragma unroll
        for (int r = 0; r < 4; ++r)
            Zc[(size_t)(row0 + lk * 4 + r) * DOUT + nt * 16 + lr] = f2bf(acc[nt][r]);

    if (t.al[s]) {
        const float* alp = t.al[s];
        float a0 = alp[lr], a1 = alp[16 + lr], a2 = alp[32 + lr], a3 = alp[48 + lr];
        #pragma unroll
        for (int r = 0; r < 4; ++r) {
            float v = acc[0][r] * a0 + acc[1][r] * a1 + acc[2][r] * a2 + acc[3][r] * a3;
            v += __shfl_xor(v, 1, 64); v += __shfl_xor(v, 2, 64);
            v += __shfl_xor(v, 4, 64); v += __shfl_xor(v, 8, 64);
            if (lr == r) t.el[s][row0 + lk * 4 + r] = v;
        }
    }
    if (t.ar[s]) {
        const float* arp = t.ar[s];
        float a0 = arp[lr], a1 = arp[16 + lr], a2 = arp[32 + lr], a3 = arp[48 + lr];
        #pragma unroll
        for (int r = 0; r < 4; ++r) {
            float v = acc[0][r] * a0 + acc[1][r] * a1 + acc[2][r] * a2 + acc[3][r] * a3;
            v += __shfl_xor(v, 1, 64); v += __shfl_xor(v, 2, 64);
            v += __shfl_xor(v, 4, 64); v += __shfl_xor(v, 8, 64);
            if (lr == r) t.er[s][row0 + lk * 4 + r] = v;
        }
    }
}

// ---------------- fused CSR/ELL gather layer 2 over 3 segments ----------------
struct GA2 {
    const int* rp[3]; const int* degp; int gbase[3]; int ell;
    const ushort_t* zc[3]; const float* el[3]; const float* er[3];
    int N[3]; int b1, b2;
};
__global__ __launch_bounds__(256) void gat2_all(GA2 t, const unsigned* __restrict__ adj,
                                                const float* __restrict__ b2t,
                                                float* __restrict__ ACCw,
                                                float* __restrict__ ACCr,
                                                void* __restrict__ out,
                                                const int* __restrict__ flagp) {
    __shared__ float atl[4][CAP];
    __shared__ int   snl[4][CAP];
    int s, b;
    if (blockIdx.x < (unsigned)t.b1) { s = 0; b = blockIdx.x; }
    else if (blockIdx.x < (unsigned)t.b2) { s = 1; b = blockIdx.x - t.b1; }
    else { s = 2; b = blockIdx.x - t.b2; }
    const int w = threadIdx.x >> 6, lane = threadIdx.x & 63;
    const int n = b * 4 + w;
    if (n >= t.N[s]) return;
    const float* el = t.el[s];
    const ushort_t* zb = t.zc[s];
    int beg, deg;
    if (t.ell) {
        int g = t.gbase[s] + n;
        beg = g * ELLW;
        deg = t.degp[g];
        deg = deg < ELLW ? deg : ELLW;
    } else {
        const int* rp = t.rp[s];
        beg = rp[n];
        deg = rp[n + 1] - beg;
    }
    const float ern = t.er[s][n];

    float ssum = 0.f;
    for (int base = 0; base < deg; base += 64) {
        int i = base + lane;
        if (i < deg) {
            unsigned ae = adj[beg + i];
            int sn = ae & 0xFFFF;
            float x = lrelu_exp(el[sn] + ern);
            ssum += x;
            if (i < CAP) {
                atl[w][i] = x * bf2f((ushort_t)(ae >> 16));
                snl[w][i] = sn;
            }
        }
    }
    #pragma unroll
    for (int o = 32; o > 0; o >>= 1) ssum += __shfl_xor(ssum, o, 64);
    const float inv = 1.f / (ssum + 1e-9f);

    const int eoff = lane >> 4;
    const int c4 = (lane & 15) * 4;
    const int degc = deg < CAP ? deg : CAP;
    float a0 = 0.f, a1 = 0.f, a2 = 0.f, a3 = 0.f;
    #pragma unroll 2
    for (int i = 0; i < degc; i += 4) {
        int ii = i + eoff;
        int iic = ii < degc ? ii : degc - 1;
        float atv = ii < degc ? atl[w][iic] : 0.f;
        int sn = snl[w][iic];
        ushort4 zv = *(const ushort4*)(zb + (size_t)sn * DOUT + c4);
        a0 += bf2f(zv.x) * atv; a1 += bf2f(zv.y) * atv;
        a2 += bf2f(zv.z) * atv; a3 += bf2f(zv.w) * atv;
    }
    for (int i = CAP; i < deg; i += 4) {
        int ii = i + eoff;
        int iic = ii < deg ? ii : deg - 1;
        unsigned ae = adj[beg + iic];
        int sn = ae & 0xFFFF;
        float atv = lrelu_exp(el[sn] + ern) * bf2f((ushort_t)(ae >> 16));
        if (ii >= deg) atv = 0.f;
        ushort4 zv = *(const ushort4*)(zb + (size_t)sn * DOUT + c4);
        a0 += bf2f(zv.x) * atv; a1 += bf2f(zv.y) * atv;
        a2 += bf2f(zv.z) * atv; a3 += bf2f(zv.w) * atv;
    }
    a0 += __shfl_xor(a0, 16, 64); a0 += __shfl_xor(a0, 32, 64);
    a1 += __shfl_xor(a1, 16, 64); a1 += __shfl_xor(a1, 32, 64);
    a2 += __shfl_xor(a2, 16, 64); a2 += __shfl_xor(a2, 32, 64);
    a3 += __shfl_xor(a3, 16, 64); a3 += __shfl_xor(a3, 32, 64);
    a0 *= inv; a1 *= inv; a2 *= inv; a3 *= inv;

    if (lane < 16) {
        size_t o = (size_t)n * DOUT + c4;
        if (s == 0) {
            float v0 = a0 + b2t[c4], v1 = a1 + b2t[c4 + 1];
            float v2 = a2 + b2t[c4 + 2], v3 = a3 + b2t[c4 + 3];
            if (flagp[0]) { *(float4*)((float*)out + o) = make_float4(v0, v1, v2, v3); }
            else {
                ushort4 ov;
                ov.x = f2bf(v0); ov.y = f2bf(v1); ov.z = f2bf(v2); ov.w = f2bf(v3);
                *(ushort4*)((ushort_t*)out + o) = ov;
            }
        } else if (s == 1) {
            *(float4*)(ACCw + o) = make_float4(a0, a1, a2, a3);
        } else {
            *(float4*)(ACCr + o) = make_float4(a0, a1, a2, a3);
        }
    }
}

__global__ __launch_bounds__(256) void out_word(const float* __restrict__ aw,
                                                const float* __restrict__ bw,
                                                const float* __restrict__ ar_,
                                                const float* __restrict__ br,
                                                void* __restrict__ out,
                                                const int* __restrict__ flagp, int total) {
    int i = blockIdx.x * 256 + threadIdx.x;
    if (i >= total) return;
    int c = i & 63;
    float v = ((aw[i] + bw[c]) + (ar_[i] + br[c])) * 0.5f;
    size_t o = (size_t)N_AC * DOUT + i;
    if (flagp[0]) ((float*)out)[o] = v;
    else ((ushort_t*)out)[o] = f2bf(v);
}

// ---------------- host launch ----------------
extern "C" void kernel_launch(void* const* d_in, const int* in_sizes, int n_in,
                              void* d_out, int out_size, void* d_ws, size_t ws_size,
                              hipStream_t stream) {
    (void)in_sizes; (void)n_in; (void)out_size;

    const void* x_ac = d_in[0];
    const void* x_w  = d_in[1];
    const void* ew_tic = d_in[2];
    const void* ew_w   = d_in[3];
    const void* ew_rel = d_in[4];
    const int* src_tic = (const int*)d_in[29];
    const int* dst_tic = (const int*)d_in[30];
    const int* src_w   = (const int*)d_in[31];
    const int* dst_w   = (const int*)d_in[32];
    const int* src_rel = (const int*)d_in[33];
    const int* dst_rel = (const int*)d_in[34];

    float* ws = (float*)d_ws;
    int* FLAG = (int*)ws;

    float* PAR = ws + 16;
    const int o_W1t = 1000000, o_W1w = 1032768, o_W1r = 1065536;
    const int o_W2t = 1098304, o_W2w = 1114688, o_W2r = 1131072;
    const int o_al1t = 1147456, o_ar1t = 1147712, o_al1w = 1147968, o_ar1w = 1148224,
              o_al1r = 1148480, o_ar1r = 1148736;
    const int o_b1t = 1148992, o_b1w = 1149248, o_b1r = 1149504;
    const int o_al2t = 1149760, o_ar2t = 1149824, o_al2w = 1149888, o_ar2w = 1149952,
              o_al2r = 1150016, o_ar2r = 1150080;
    const int o_b2t = 1150144, o_b2w = 1150208, o_b2r = 1150272;
    const int o_qer1r = 1150400, o_qer2r = 1150912;

    float* EB   = ws + 1160016;
    float* ELt  = EB;
    float* ERt  = EB + 160000;
    float* ELw  = EB + 320000;
    float* ERw  = EB + 400000;
    float* ELr  = EB + 480000;
    float* ERr  = EB + 640000;
    float* E2tl = EB + 720000;
    float* E2tr = EB + 760000;
    float* E2wl = EB + 800000;
    float* E2wr = EB + 820000;
    float* E2rl = EB + 840000;
    float* E2rr = EB + 880000;

    const size_t NEED_A = 27813744ull * 4ull;   // 111.3 MB
    const bool pathA = ws_size >= NEED_A;

    // ---- P0 (shared) ----
    detect_dtype<<<1, 256, 0, stream>>>((const ushort_t*)x_ac, FLAG);

    CvtTab ct;
    const int srcIdx[24] = {5,6,7,8, 9,10,11,12, 13,14,15,16,
                            17,18,19,20, 21,22,23,24, 25,26,27,28};
    const int sizes[24] = {32768,256,256,256, 32768,256,256,256, 32768,256,256,256,
                           16384,64,64,64, 16384,64,64,64, 16384,64,64,64};
    const int offs[24] = {o_W1t,o_al1t,o_ar1t,o_b1t, o_W1w,o_al1w,o_ar1w,o_b1w,
                          o_W1r,o_al1r,o_ar1r,o_b1r,
                          o_W2t,o_al2t,o_ar2t,o_b2t, o_W2w,o_al2w,o_ar2w,o_b2w,
                          o_W2r,o_al2r,o_ar2r,o_b2r};
    for (int i = 0; i < 24; ++i) { ct.src[i] = d_in[srcIdx[i]]; ct.n[i] = sizes[i]; ct.off[i] = offs[i]; }
    cvt_inputs<<<24 * 8, 256, 0, stream>>>(ct, PAR, FLAG);

    QTab qt;
    qt.woff[0] = o_W1r; qt.aoff[0] = o_ar1r; qt.qoff[0] = o_qer1r; qt.K[0] = 128; qt.Hh[0] = 4;
    qt.woff[1] = o_W2r; qt.aoff[1] = o_ar2r; qt.qoff[1] = o_qer2r; qt.K[1] = 256; qt.Hh[1] = 1;
    make_q<<<2, 256, 0, stream>>>(qt, PAR);

    if (pathA) {
        ushort_t* Z_tic = (ushort_t*)(ws + 2060016);
        ushort_t* Z_w   = (ushort_t*)(ws + 7180016);
        ushort_t* Z_rel = (ushort_t*)(ws + 9740016);
        float* ACCw = ws + 9740016;                    // aliases Z_rel (dead after gat1<2>)
        float* ACCr = ws + 11020016;
        ushort_t* Hac = (ushort_t*)(ws + 14860016);
        ushort_t* Hw  = (ushort_t*)(ws + 19980016);
        ushort_t* WT  = (ushort_t*)(ws + 22540016);
        int* cntA = (int*)(ws + 22613744);             // N_ALL
        unsigned* adjA = (unsigned*)(ws + 22693744);   // N_ALL*ELLW -> ends 27813744
        ushort_t* Zc_tic = Z_tic;
        ushort_t* Zc_w   = Z_tic + 2560000;
        ushort_t* Zc_r   = Z_tic + 3840000;
        const int t_W1t = 0, t_W1w = 32768, t_W1r = 65536,
                  t_W2t = 98304, t_W2w = 114688, t_W2r = 131072;

        PTab pt;
        const int pw[6] = {o_W1t, o_W1w, o_W1r, o_W2t, o_W2w, o_W2r};
        const int ptf[6] = {t_W1t, t_W1w, t_W1r, t_W2t, t_W2w, t_W2r};
        for (int i = 0; i < 6; ++i) {
            pt.woff[i] = pw[i]; pt.toff[i] = ptf[i];
            pt.Klog[i] = (i < 3) ? 7 : 8; pt.N[i] = (i < 3) ? 256 : 64;
        }
        pack_wt<<<6 * 16, 256, 0, stream>>>(pt, PAR, WT);

        hipMemsetAsync(cntA, 0, N_ALL * 4, stream);

        // ---- fused front-end: 3x mgemm1 + elr1 FIRST, range-restricted fill LAST ----
        FA fa;
        fa.s0 = src_tic; fa.d0 = dst_tic; fa.w0 = ew_tic;
        fa.s1 = src_w;   fa.d1 = dst_w;   fa.w1 = ew_w;
        fa.s2 = src_rel; fa.d2 = dst_rel; fa.w2 = ew_rel;
        fa.flagp = FLAG; fa.cnt = cntA; fa.adj = adjA;
        fa.x_ac = x_ac; fa.x_w = x_w;
        fa.WTt = WT + t_W1t; fa.WTw = WT + t_W1w; fa.WTr = WT + t_W1r;
        fa.Zt = Z_tic; fa.Zw = Z_w; fa.Zr = Z_rel;
        fa.al1t = PAR + o_al1t; fa.ar1t = PAR + o_ar1t;
        fa.al1w = PAR + o_al1w; fa.ar1w = PAR + o_ar1w;
        fa.al1r = PAR + o_al1r;
        fa.ELt = ELt; fa.ERt = ERt; fa.ELw = ELw; fa.ERw = ERw;
        fa.ELr = ELr; fa.ERr = ERr;
        fa.qer1r = PAR + o_qer1r;
        fa.c0 = N_AC / 16;                 // mgemm1 tic
        fa.c1 = fa.c0 + N_W / 16;          // mgemm1 w
        fa.c2 = fa.c1 + N_AC / 16;         // mgemm1 rel
        fa.c3 = fa.c2 + N_W / 4;           // elr1
        const unsigned ctot = fa.c3 + FILL_BLOCKS;   // fill last
        fused_a<<<ctot, 256, 0, stream>>>(fa);

        // ---- layer-1 gathers: tic+w fused, then rel (+E2rr epilogue) ----
        GT gt;
        gt.degp = cntA; gt.adj = adjA;
        gt.Zt = Z_tic; gt.Zw = Z_w;
        gt.ELt = ELt; gt.ERt = ERt; gt.ELw = ELw; gt.ERw = ERw;
        gt.b1t = PAR + o_b1t; gt.b1w = PAR + o_b1w;
        gt.Hac = Hac; gt.Hw = Hw;
        gt.b1 = N_AC / 4;
        gat1_tw<<<N_AC / 4 + N_W / 4, 256, 0, stream>>>(gt);

        gat1<2><<<N_W / 4, 256, 0, stream>>>(nullptr, cntA, N_AC + N_W, 1, adjA, Z_rel,
                                             ELr, ERr, PAR + o_b1r, Hw, N_W,
                                             PAR + o_qer2r, E2rr);

        // ---- layer 2 ----
        G2 g2;
        g2.Hb[0] = Hac; g2.Hb[1] = Hw; g2.Hb[2] = Hac;
        g2.WT[0] = WT + t_W2t; g2.WT[1] = WT + t_W2w; g2.WT[2] = WT + t_W2r;
        g2.Zc[0] = Zc_tic; g2.Zc[1] = Zc_w; g2.Zc[2] = Zc_r;
        g2.al[0] = PAR + o_al2t; g2.al[1] = PAR + o_al2w; g2.al[2] = PAR + o_al2r;
        g2.ar[0] = PAR + o_ar2t; g2.ar[1] = PAR + o_ar2w; g2.ar[2] = nullptr;
        g2.el[0] = E2tl; g2.el[1] = E2wl; g2.el[2] = E2rl;
        g2.er[0] = E2tr; g2.er[1] = E2wr; g2.er[2] = nullptr;
        g2.N[0] = N_AC; g2.N[1] = N_W; g2.N[2] = N_AC;
        const int nb0 = (N_AC + 63) / 64, nb1 = (N_W + 63) / 64, nb2 = (N_AC + 63) / 64;
        g2.b1 = nb0; g2.b2 = nb0 + nb1;
        mgemm2_all<<<nb0 + nb1 + nb2, 256, 0, stream>>>(g2);

        GA2 ga;
        ga.rp[0] = ga.rp[1] = ga.rp[2] = nullptr;
        ga.degp = cntA; ga.ell = 1;
        ga.gbase[0] = 0; ga.gbase[1] = N_AC; ga.gbase[2] = N_AC + N_W;
        ga.zc[0] = Zc_tic; ga.zc[1] = Zc_w; ga.zc[2] = Zc_r;
        ga.el[0] = E2tl; ga.el[1] = E2wl; ga.el[2] = E2rl;
        ga.er[0] = E2tr; ga.er[1] = E2wr; ga.er[2] = E2rr;
        ga.N[0] = N_AC; ga.N[1] = N_W; ga.N[2] = N_W;
        const int gb0 = N_AC / 4, gb1 = N_W / 4, gb2 = N_W / 4;
        ga.b1 = gb0; ga.b2 = gb0 + gb1;
        gat2_all<<<gb0 + gb1 + gb2, 256, 0, stream>>>(ga, adjA, PAR + o_b2t, ACCw, ACCr, d_out, FLAG);

        out_word<<<(N_W * DOUT) / 256, 256, 0, stream>>>(ACCw, PAR + o_b2w, ACCr, PAR + o_b2r,
                                                         d_out, FLAG, N_W * DOUT);
    } else {
        // ---------- PATH B: round-12 proven flow ----------
        float* ACC = ws + 2060016;
        ushort_t* Zb  = (ushort_t*)(ws + 3340016);
        ushort_t* Hac = (ushort_t*)(ws + 8460016);
        ushort_t* Hw  = (ushort_t*)(ws + 13580016);
        ushort_t* WT  = (ushort_t*)(ws + 16140016);
        const int t_W1t = 0, t_W1w = 32768, t_W1r = 65536,
                  t_W2t = 98304, t_W2w = 114688, t_W2r = 131072;
        int* IB = (int*)(ws + 16213760);
        int* rp   = IB;
        int* cnt  = IB + 80064;
        int* bsum = IB + 160128;
        unsigned* adj = (unsigned*)(IB + 160704);
        int* rank = IB + 1160704;
        float* ACCr = ws + 18374464;
        ushort_t* Zc_tic = Zb;
        ushort_t* Zc_w   = Zb + 2560000;
        ushort_t* Zc_r   = Zb + 3840000;

        PTab pt;
        const int pw[6] = {o_W1t, o_W1w, o_W1r, o_W2t, o_W2w, o_W2r};
        const int ptf[6] = {t_W1t, t_W1w, t_W1r, t_W2t, t_W2w, t_W2r};
        for (int i = 0; i < 6; ++i) {
            pt.woff[i] = pw[i]; pt.toff[i] = ptf[i];
            pt.Klog[i] = (i < 3) ? 7 : 8; pt.N[i] = (i < 3) ? 256 : 64;
        }
        pack_wt<<<6 * 16, 256, 0, stream>>>(pt, PAR, WT);

        {
            const int B = (N_ALL + 255) / 256;
            hipMemsetAsync(cnt, 0, N_ALL * 4, stream);
            count3<<<(E_ALL + 255) / 256, 256, 0, stream>>>(dst_tic, dst_w, dst_rel, cnt, rank);
            scan_bsum<<<B, 256, 0, stream>>>(cnt, bsum, N_ALL);
            scan_top<<<1, 512, 0, stream>>>(bsum, B);
            scan_out<<<B, 256, 0, stream>>>(cnt, bsum, rp, N_ALL);
            fill3<<<8 * ((E_ALL + FCH - 1) / FCH), 256, 0, stream>>>(
                src_tic, dst_tic, ew_tic, src_w, dst_w, ew_w, src_rel, dst_rel, ew_rel,
                FLAG, rp, rank, adj);
        }
        const int* rp_tic = rp;
        const int* rp_w   = rp + N_AC;
        const int* rp_rel = rp + N_AC + N_W;

        elr1<<<N_W / 4, 256, 0, stream>>>(x_w, FLAG, PAR + o_qer1r, ERr, N_W, 128, 4);

        mgemm1<<<N_AC / 16, 256, 0, stream>>>(x_ac, FLAG, WT + t_W1t, Zb,
                                              PAR + o_al1t, PAR + o_ar1t, ELt, ERt);
        gat1<0><<<N_AC / 4, 256, 0, stream>>>(rp_tic, nullptr, 0, 0, adj, Zb,
                                              ELt, ERt, PAR + o_b1t, Hac, N_AC, nullptr, nullptr);

        mgemm1<<<N_W / 16, 256, 0, stream>>>(x_w, FLAG, WT + t_W1w, Zb,
                                             PAR + o_al1w, PAR + o_ar1w, ELw, ERw);
        gat1<1><<<N_W / 4, 256, 0, stream>>>(rp_w, nullptr, 0, 0, adj, Zb,
                                             ELw, ERw, PAR + o_b1w, Hw, N_W, nullptr, nullptr);

        mgemm1<<<N_AC / 16, 256, 0, stream>>>(x_ac, FLAG, WT + t_W1r, Zb,
                                              PAR + o_al1r, nullptr, ELr, nullptr);
        gat1<2><<<N_W / 4, 256, 0, stream>>>(rp_rel, nullptr, 0, 0, adj, Zb,
                                             ELr, ERr, PAR + o_b1r, Hw, N_W,
                                             PAR + o_qer2r, E2rr);

        G2 g2;
        g2.Hb[0] = Hac; g2.Hb[1] = Hw; g2.Hb[2] = Hac;
        g2.WT[0] = WT + t_W2t; g2.WT[1] = WT + t_W2w; g2.WT[2] = WT + t_W2r;
        g2.Zc[0] = Zc_tic; g2.Zc[1] = Zc_w; g2.Zc[2] = Zc_r;
        g2.al[0] = PAR + o_al2t; g2.al[1] = PAR + o_al2w; g2.al[2] = PAR + o_al2r;
        g2.ar[0] = PAR + o_ar2t; g2.ar[1] = PAR + o_ar2w; g2.ar[2] = nullptr;
        g2.el[0] = E2tl; g2.el[1] = E2wl; g2.el[2] = E2rl;
        g2.er[0] = E2tr; g2.er[1] = E2wr; g2.er[2] = nullptr;
        g2.N[0] = N_AC; g2.N[1] = N_W; g2.N[2] = N_AC;
        const int nb0 = (N_AC + 63) / 64, nb1 = (N_W + 63) / 64, nb2 = (N_AC + 63) / 64;
        g2.b1 = nb0; g2.b2 = nb0 + nb1;
        mgemm2_all<<<nb0 + nb1 + nb2, 256, 0, stream>>>(g2);

        GA2 ga;
        ga.rp[0] = rp_tic; ga.rp[1] = rp_w; ga.rp[2] = rp_rel;
        ga.degp = nullptr; ga.ell = 0;
        ga.gbase[0] = ga.gbase[1] = ga.gbase[2] = 0;
        ga.zc[0] = Zc_tic; ga.zc[1] = Zc_w; ga.zc[2] = Zc_r;
        ga.el[0] = E2tl; ga.el[1] = E2wl; ga.el[2] = E2rl;
        ga.er[0] = E2tr; ga.er[1] = E2wr; ga.er[2] = E2rr;
        ga.N[0] = N_AC; ga.N[1] = N_W; ga.N[2] = N_W;
        const int gb0 = N_AC / 4, gb1 = N_W / 4, gb2 = N_W / 4;
        ga.b1 = gb0; ga.b2 = gb0 + gb1;
        gat2_all<<<gb0 + gb1 + gb2, 256, 0, stream>>>(ga, adj, PAR + o_b2t, ACC, ACCr, d_out, FLAG);

        out_word<<<(N_W * DOUT) / 256, 256, 0, stream>>>(ACC, PAR + o_b2w, ACCr, PAR + o_b2r,
                                                         d_out, FLAG, N_W * DOUT);
    }
}

// Round 20
// 309.094 us; speedup vs baseline: 1.0781x; 1.0781x over previous
//
#include <hip/hip_runtime.h>
#include <hip/hip_bf16.h>

typedef unsigned short ushort_t;
typedef __attribute__((ext_vector_type(8))) short bf16x8;
typedef __attribute__((ext_vector_type(4))) float f32x4;

// ---------------- constants ----------------
#define N_AC 40000
#define N_W  20000
#define D_IN 128
#define NH   4
#define HD   256
#define DOUT 64
#define E_TIC 400000
#define E_W   200000
#define E_REL 400000
#define E_ALL 1000000
#define N_ALL 80000
#define NEG 0.2f
#define CAP 96
#define FCH 4096
#define ELLW 64

__device__ __forceinline__ float bf2f(ushort_t u) {
    return __uint_as_float(((unsigned int)u) << 16);
}
__device__ __forceinline__ ushort_t f2bf(float v) {
    unsigned u = __float_as_uint(v);
    unsigned r = (u + 0x7fffu + ((u >> 16) & 1u)) >> 16;
    return (ushort_t)r;
}
__device__ __forceinline__ float ldf(const void* p, size_t i, int f) {
    return f ? ((const float*)p)[i] : bf2f(((const ushort_t*)p)[i]);
}
__device__ __forceinline__ float lrelu_exp(float v) {
    v = v > 0.f ? v : NEG * v;
    return __expf(v);
}

// ---------------- dtype autodetect ----------------
__global__ void detect_dtype(const ushort_t* __restrict__ x, int* __restrict__ flag) {
    __shared__ int hit;
    if (threadIdx.x == 0) hit = 0;
    __syncthreads();
    for (int i = threadIdx.x; i < 4096; i += 256) {
        float v = bf2f(x[i]);
        if (!(fabsf(v) <= 1e4f)) atomicOr(&hit, 1);
    }
    __syncthreads();
    if (threadIdx.x == 0) flag[0] = hit ? 1 : 0;
}

// ---------------- canonicalize 24 small param tensors to f32 ----------------
struct CvtTab { const void* src[24]; int n[24]; int off[24]; };
__global__ __launch_bounds__(256) void cvt_inputs(CvtTab t, float* __restrict__ par,
                                                  const int* __restrict__ flagp) {
    int ent = blockIdx.x >> 3, sub = blockIdx.x & 7;
    int f = flagp[0];
    const void* s = t.src[ent];
    int n = t.n[ent];
    float* d = par + t.off[ent];
    for (int i = sub * 256 + threadIdx.x; i < n; i += 8 * 256)
        d[i] = f ? ((const float*)s)[i] : bf2f(((const ushort_t*)s)[i]);
}

// ---------------- q vectors (rel-dst cases only) ----------------
struct QTab { int woff[2]; int aoff[2]; int qoff[2]; int K[2]; int Hh[2]; };
__global__ __launch_bounds__(256) void make_q(QTab t, float* __restrict__ par) {
    int b = blockIdx.x;
    int k = threadIdx.x;
    int K = t.K[b], Hh = t.Hh[b];
    if (k >= K) return;
    const float* W = par + t.woff[b];
    const float* a = par + t.aoff[b];
    float* q = par + t.qoff[b];
    int HDc = Hh * 64;
    for (int h = 0; h < Hh; ++h) {
        float s = 0.f;
        for (int d = 0; d < 64; ++d) s += W[(size_t)k * HDc + h * 64 + d] * a[h * 64 + d];
        q[k * Hh + h] = s;
    }
}

// ---------------- pack W^T to bf16 (N x K row-major) ----------------
struct PTab { int woff[6]; int toff[6]; int Klog[6]; int N[6]; };
__global__ __launch_bounds__(256) void pack_wt(PTab t, const float* __restrict__ par,
                                               ushort_t* __restrict__ wt) {
    int m = blockIdx.x >> 4, sub = blockIdx.x & 15;
    int Klog = t.Klog[m], K = 1 << Klog, Nn = t.N[m];
    int tot = K * Nn;
    const float* Wp = par + t.woff[m];
    ushort_t* d = wt + t.toff[m];
    for (int i = sub * 256 + threadIdx.x; i < tot; i += 16 * 256) {
        int n = i >> Klog, k = i & (K - 1);
        d[i] = f2bf(Wp[(size_t)k * Nn + n]);
    }
}

// ================= device bodies =========

__device__ __forceinline__ void dev_mgemm1(int b, const void* X, int f,
                                           const ushort_t* WT, ushort_t* Zb,
                                           const float* alp, const float* arp,
                                           float* elo, float* ero) {
    const int w = threadIdx.x >> 6, l = threadIdx.x & 63;
    const int row0 = b * 16;
    const int lr = l & 15, lk = l >> 4;

    bf16x8 a[4];
    if (!f) {
        const ushort_t* xp = (const ushort_t*)X + (size_t)(row0 + lr) * 128 + lk * 8;
        #pragma unroll
        for (int ks = 0; ks < 4; ++ks) a[ks] = *(const bf16x8*)(xp + ks * 32);
    } else {
        const float* xp = (const float*)X + (size_t)(row0 + lr) * 128 + lk * 8;
        #pragma unroll
        for (int ks = 0; ks < 4; ++ks)
            #pragma unroll
            for (int j = 0; j < 8; ++j) a[ks][j] = (short)f2bf(xp[ks * 32 + j]);
    }

    f32x4 acc[4] = {{0.f,0.f,0.f,0.f},{0.f,0.f,0.f,0.f},{0.f,0.f,0.f,0.f},{0.f,0.f,0.f,0.f}};
    const int col0 = w * 64;
    #pragma unroll
    for (int ks = 0; ks < 4; ++ks) {
        #pragma unroll
        for (int nt = 0; nt < 4; ++nt) {
            bf16x8 bb = *(const bf16x8*)(WT + (size_t)(col0 + nt * 16 + lr) * 128 + ks * 32 + lk * 8);
            acc[nt] = __builtin_amdgcn_mfma_f32_16x16x32_bf16(a[ks], bb, acc[nt], 0, 0, 0);
        }
    }
    #pragma unroll
    for (int nt = 0; nt < 4; ++nt)
        #pragma unroll
        for (int r = 0; r < 4; ++r)
            Zb[(size_t)(row0 + lk * 4 + r) * HD + col0 + nt * 16 + lr] = f2bf(acc[nt][r]);

    if (alp) {
        float a0 = alp[col0 + lr], a1 = alp[col0 + 16 + lr],
              a2 = alp[col0 + 32 + lr], a3 = alp[col0 + 48 + lr];
        #pragma unroll
        for (int r = 0; r < 4; ++r) {
            float v = acc[0][r] * a0 + acc[1][r] * a1 + acc[2][r] * a2 + acc[3][r] * a3;
            v += __shfl_xor(v, 1, 64); v += __shfl_xor(v, 2, 64);
            v += __shfl_xor(v, 4, 64); v += __shfl_xor(v, 8, 64);
            if (lr == r) elo[(size_t)(row0 + lk * 4 + r) * 4 + w] = v;
        }
    }
    if (arp) {
        float a0 = arp[col0 + lr], a1 = arp[col0 + 16 + lr],
              a2 = arp[col0 + 32 + lr], a3 = arp[col0 + 48 + lr];
        #pragma unroll
        for (int r = 0; r < 4; ++r) {
            float v = acc[0][r] * a0 + acc[1][r] * a1 + acc[2][r] * a2 + acc[3][r] * a3;
            v += __shfl_xor(v, 1, 64); v += __shfl_xor(v, 2, 64);
            v += __shfl_xor(v, 4, 64); v += __shfl_xor(v, 8, 64);
            if (lr == r) ero[(size_t)(row0 + lk * 4 + r) * 4 + w] = v;
        }
    }
}

// class-partitioned ELL fill with etype-aware edge ranges (round-18 proven).
__device__ __forceinline__ void dev_fill_ell(int b,
        const int* s0, const int* d0, const void* w0,
        const int* s1, const int* d1, const void* w1,
        const int* s2, const int* d2, const void* w2,
        int f, int* cnt, unsigned* adj) {
    const int CB[9]  = {0, 12500, 25000, 37500, 50000, 61250, 67500, 73750, 80000};
    const int F[9]   = {0, 98, 196, 294, 441, 589, 688, 787, 886};
    const int CLO[8] = {0, 0, 0, 0, 97, 146, 146, 146};
    const int ELO[8] = {0, 0, 0, 0, E_TIC, E_TIC + E_W, E_TIC + E_W, E_TIC + E_W};
    const int EHI[8] = {E_TIC, E_TIC, E_TIC, E_TIC + E_W, E_ALL, E_ALL, E_ALL, E_ALL};
    int cls = 0;
    while (b >= F[cls + 1]) ++cls;          // b < 886, uniform
    const int lo = CB[cls], hi = CB[cls + 1];
    const int eLo = ELO[cls], eHi = EHI[cls];
    const int e0 = (CLO[cls] + (b - F[cls])) * FCH;
    for (int i = threadIdx.x; i < FCH; i += 256) {
        int e = e0 + i;
        if (e < eLo || e >= eHi) continue;
        int g;
        if (e < E_TIC) g = d0[e];
        else if (e < E_TIC + E_W) g = N_AC + d1[e - E_TIC];
        else g = N_AC + N_W + d2[e - E_TIC - E_W];
        if (g < lo || g >= hi) continue;
        int sn; float ew;
        if (e < E_TIC) { sn = s0[e]; ew = ldf(w0, e, f); }
        else if (e < E_TIC + E_W) { int le = e - E_TIC; sn = s1[le]; ew = ldf(w1, le, f); }
        else { int le = e - E_TIC - E_W; sn = s2[le]; ew = ldf(w2, le, f); }
        int r = atomicAdd(&cnt[g], 1);
        if (r < ELLW)
            adj[(size_t)g * ELLW + r] = (unsigned)(sn & 0xFFFF) | ((unsigned)f2bf(ew) << 16);
    }
}
#define FILL_BLOCKS 886

__device__ __forceinline__ void dev_elr1(int b, const void* X, int f,
                                         const float* q0, float* o0,
                                         int N, int D, int Hh) {
    __shared__ float qs[512];
    const int tid = threadIdx.x;
    const int tot = D * Hh;
    for (int i = tid; i < tot; i += 256) {
        int k, h;
        if (Hh == 4) { k = i >> 2; h = i & 3; } else { k = i; h = 0; }
        qs[h * D + k] = q0[i];
    }
    __syncthreads();
    const int wid = tid >> 6, lane = tid & 63;
    const int n = b * 4 + wid;
    if (n >= N) return;
    const int J = D >> 6;
    float x[4];
    for (int j = 0; j < J; ++j) x[j] = ldf(X, (size_t)n * D + j * 64 + lane, f);
    for (int h = 0; h < Hh; ++h) {
        float v = 0.f;
        for (int j = 0; j < J; ++j) v += x[j] * qs[h * D + j * 64 + lane];
        #pragma unroll
        for (int o = 32; o > 0; o >>= 1) v += __shfl_down(v, o, 64);
        if (lane == 0) o0[n * Hh + h] = v;
    }
}

// gat1 body (ELL or CSR); MODE 2 optionally computes e2out[n] = h_word . q2
template <int MODE>
__device__ __forceinline__ void dev_gat1(int b,
        const int* rp, const int* degp, int gbase, int ell,
        const unsigned* adj, const ushort_t* zb,
        const float* el, const float* er, const float* bias,
        ushort_t* H, int N, const float* q2, float* e2out) {
    __shared__ float atl[4][CAP * 4];
    __shared__ int   snl[4][CAP];
    const int w = threadIdx.x >> 6, lane = threadIdx.x & 63;
    const int n = b * 4 + w;
    if (n >= N) return;
    const int h = lane >> 4;
    int beg, deg;
    if (ell) {
        int g = gbase + n;
        beg = g * ELLW;
        deg = degp[g];
        deg = deg < ELLW ? deg : ELLW;
    } else {
        beg = rp[n];
        deg = rp[n + 1] - beg;
    }
    const float4* el4 = (const float4*)el;
    const float4 ern = ((const float4*)er)[n];

    float4 ss = make_float4(0.f, 0.f, 0.f, 0.f);
    for (int base = 0; base < deg; base += 64) {
        int i = base + lane;
        if (i < deg) {
            unsigned ae = adj[beg + i];
            int sn = ae & 0xFFFF;
            float4 e = el4[sn];
            float x0 = lrelu_exp(e.x + ern.x);
            float x1 = lrelu_exp(e.y + ern.y);
            float x2 = lrelu_exp(e.z + ern.z);
            float x3 = lrelu_exp(e.w + ern.w);
            ss.x += x0; ss.y += x1; ss.z += x2; ss.w += x3;
            if (i < CAP) {
                float ew = bf2f((ushort_t)(ae >> 16));
                float4* dst4 = (float4*)&atl[w][i * 4];
                *dst4 = make_float4(x0 * ew, x1 * ew, x2 * ew, x3 * ew);
                snl[w][i] = sn;
            }
        }
    }
    #pragma unroll
    for (int o = 32; o > 0; o >>= 1) {
        ss.x += __shfl_xor(ss.x, o, 64);
        ss.y += __shfl_xor(ss.y, o, 64);
        ss.z += __shfl_xor(ss.z, o, 64);
        ss.w += __shfl_xor(ss.w, o, 64);
    }
    const float sh = (h == 0) ? ss.x : (h == 1) ? ss.y : (h == 2) ? ss.z : ss.w;
    const float inv = 1.f / (sh + 1e-9f);
    const float erh = (h == 0) ? ern.x : (h == 1) ? ern.y : (h == 2) ? ern.z : ern.w;

    float a0 = 0.f, a1 = 0.f, a2 = 0.f, a3 = 0.f;
    #pragma unroll 4
    for (int i = 0; i < deg; ++i) {
        int sn; float atv;
        if (i < CAP) {
            sn = snl[w][i];
            atv = atl[w][i * 4 + h];
        } else {
            unsigned ae = adj[beg + i];
            sn = ae & 0xFFFF;
            atv = lrelu_exp(el[sn * 4 + h] + erh) * bf2f((ushort_t)(ae >> 16));
        }
        ushort4 zv = *(const ushort4*)(zb + (size_t)sn * HD + lane * 4);
        a0 += bf2f(zv.x) * atv; a1 += bf2f(zv.y) * atv;
        a2 += bf2f(zv.z) * atv; a3 += bf2f(zv.w) * atv;
    }
    float4 bb = *(const float4*)(bias + lane * 4);
    a0 = a0 * inv + bb.x; a1 = a1 * inv + bb.y;
    a2 = a2 * inv + bb.z; a3 = a3 * inv + bb.w;

    ushort_t* hp = H + (size_t)n * HD + lane * 4;
    ushort4 o;
    if (MODE == 0) {
        o.x = f2bf(a0 > 0.f ? a0 : 0.f); o.y = f2bf(a1 > 0.f ? a1 : 0.f);
        o.z = f2bf(a2 > 0.f ? a2 : 0.f); o.w = f2bf(a3 > 0.f ? a3 : 0.f);
    } else if (MODE == 1) {
        o.x = f2bf(a0 > 0.f ? a0 : expm1f(a0)); o.y = f2bf(a1 > 0.f ? a1 : expm1f(a1));
        o.z = f2bf(a2 > 0.f ? a2 : expm1f(a2)); o.w = f2bf(a3 > 0.f ? a3 : expm1f(a3));
    } else {
        ushort4 hw = *(const ushort4*)hp;
        float v0 = (bf2f(hw.x) + (a0 > 0.f ? a0 : expm1f(a0))) * 0.5f;
        float v1 = (bf2f(hw.y) + (a1 > 0.f ? a1 : expm1f(a1))) * 0.5f;
        float v2 = (bf2f(hw.z) + (a2 > 0.f ? a2 : expm1f(a2))) * 0.5f;
        float v3 = (bf2f(hw.w) + (a3 > 0.f ? a3 : expm1f(a3))) * 0.5f;
        v0 = v0 > 0.f ? v0 : 0.f; v1 = v1 > 0.f ? v1 : 0.f;
        v2 = v2 > 0.f ? v2 : 0.f; v3 = v3 > 0.f ? v3 : 0.f;
        o.x = f2bf(v0); o.y = f2bf(v1); o.z = f2bf(v2); o.w = f2bf(v3);
        if (q2) {   // fused E2rr = h_word . q2
            const int c4 = lane * 4;
            float d = v0 * q2[c4] + v1 * q2[c4 + 1] + v2 * q2[c4 + 2] + v3 * q2[c4 + 3];
            #pragma unroll
            for (int oo = 32; oo > 0; oo >>= 1) d += __shfl_xor(d, oo, 64);
            if (lane == 0) e2out[n] = d;
        }
    }
    *(ushort4*)hp = o;
}

// ================= fused front-end (path A): fill FIRST (overlapped) =========
struct FA {
    const int *s0, *d0; const void* w0;
    const int *s1, *d1; const void* w1;
    const int *s2, *d2; const void* w2;
    const int* flagp; int* cnt; unsigned* adj;
    const void* x_ac; const void* x_w;
    const ushort_t *WTt, *WTw, *WTr;
    ushort_t *Zt, *Zw, *Zr;
    const float *al1t, *ar1t, *al1w, *ar1w, *al1r;
    float *ELt, *ERt, *ELw, *ERw, *ELr, *ERr;
    const float* qer1r;
    unsigned c0, c1, c2, c3;
};
__global__ __launch_bounds__(256) void fused_a(FA a) {
    const unsigned b = blockIdx.x;
    const int f = a.flagp[0];
    if (b < a.c0) {
        dev_fill_ell(b, a.s0, a.d0, a.w0, a.s1, a.d1, a.w1, a.s2, a.d2, a.w2,
                     f, a.cnt, a.adj);
    } else if (b < a.c1) {
        dev_mgemm1(b - a.c0, a.x_ac, f, a.WTt, a.Zt, a.al1t, a.ar1t, a.ELt, a.ERt);
    } else if (b < a.c2) {
        dev_mgemm1(b - a.c1, a.x_w, f, a.WTw, a.Zw, a.al1w, a.ar1w, a.ELw, a.ERw);
    } else if (b < a.c3) {
        dev_mgemm1(b - a.c2, a.x_ac, f, a.WTr, a.Zr, a.al1r, nullptr, a.ELr, nullptr);
    } else {
        dev_elr1(b - a.c3, a.x_w, f, a.qer1r, a.ERr, N_W, 128, 4);
    }
}

// fused gat1 tic+w (ELL mode)
struct GT {
    const int* degp; const unsigned* adj;
    const ushort_t *Zt, *Zw;
    const float *ELt, *ERt, *ELw, *ERw, *b1t, *b1w;
    ushort_t *Hac, *Hw;
    unsigned b1;
};
__global__ __launch_bounds__(256) void gat1_tw(GT t) {
    if (blockIdx.x < t.b1)
        dev_gat1<0>(blockIdx.x, nullptr, t.degp, 0, 1, t.adj, t.Zt,
                    t.ELt, t.ERt, t.b1t, t.Hac, N_AC, nullptr, nullptr);
    else
        dev_gat1<1>(blockIdx.x - t.b1, nullptr, t.degp, N_AC, 1, t.adj, t.Zw,
                    t.ELw, t.ERw, t.b1w, t.Hw, N_W, nullptr, nullptr);
}

// standalone gat1 wrapper (path B + path A rel)
template <int MODE>
__global__ __launch_bounds__(256) void gat1(const int* __restrict__ rp,
                                            const int* __restrict__ degp,
                                            int gbase, int ell,
                                            const unsigned* __restrict__ adj,
                                            const ushort_t* __restrict__ zb,
                                            const float* __restrict__ el,
                                            const float* __restrict__ er,
                                            const float* __restrict__ bias,
                                            ushort_t* __restrict__ H, int N,
                                            const float* __restrict__ q2,
                                            float* __restrict__ e2out) {
    dev_gat1<MODE>(blockIdx.x, rp, degp, gbase, ell, adj, zb, el, er, bias, H, N, q2, e2out);
}

// ================= path-B CSR build (round-12 proven form) =================
__global__ __launch_bounds__(256) void count3(const int* __restrict__ d0,
                                              const int* __restrict__ d1,
                                              const int* __restrict__ d2,
                                              int* __restrict__ cnt,
                                              int* __restrict__ rank) {
    int e = blockIdx.x * 256 + threadIdx.x;
    if (e >= E_ALL) return;
    int g;
    if (e < E_TIC) g = d0[e];
    else if (e < E_TIC + E_W) g = N_AC + d1[e - E_TIC];
    else g = N_AC + N_W + d2[e - E_TIC - E_W];
    rank[e] = atomicAdd(&cnt[g], 1);
}

__global__ __launch_bounds__(256) void scan_bsum(const int* __restrict__ cnt,
                                                 int* __restrict__ bsum, int N) {
    __shared__ int red[256];
    int i = blockIdx.x * 256 + threadIdx.x;
    red[threadIdx.x] = (i < N) ? cnt[i] : 0;
    __syncthreads();
    #pragma unroll
    for (int o = 128; o > 0; o >>= 1) {
        if (threadIdx.x < o) red[threadIdx.x] += red[threadIdx.x + o];
        __syncthreads();
    }
    if (threadIdx.x == 0) bsum[blockIdx.x] = red[0];
}

__global__ __launch_bounds__(512) void scan_top(int* __restrict__ bsum, int B) {
    __shared__ int sc[512];
    const int t = threadIdx.x;
    int v = (t < B) ? bsum[t] : 0;
    sc[t] = v;
    __syncthreads();
    #pragma unroll
    for (int o = 1; o < 512; o <<= 1) {
        int u = (t >= o) ? sc[t - o] : 0;
        __syncthreads();
        sc[t] += u;
        __syncthreads();
    }
    if (t < B) bsum[t] = sc[t] - v;
}

__global__ __launch_bounds__(256) void scan_out(const int* __restrict__ cnt,
                                                const int* __restrict__ bsum,
                                                int* __restrict__ rowptr, int N) {
    __shared__ int sc[256];
    const int t = threadIdx.x;
    int i = blockIdx.x * 256 + t;
    int v = (i < N) ? cnt[i] : 0;
    sc[t] = v;
    __syncthreads();
    #pragma unroll
    for (int o = 1; o < 256; o <<= 1) {
        int u = (t >= o) ? sc[t - o] : 0;
        __syncthreads();
        sc[t] += u;
        __syncthreads();
    }
    int ex = sc[t] - v + bsum[blockIdx.x];
    if (i < N) {
        rowptr[i] = ex;
        if (i == N - 1) rowptr[N] = ex + v;
    }
}

__global__ __launch_bounds__(256) void fill3(const int* __restrict__ s0, const int* __restrict__ d0, const void* __restrict__ w0,
                                             const int* __restrict__ s1, const int* __restrict__ d1, const void* __restrict__ w1,
                                             const int* __restrict__ s2, const int* __restrict__ d2, const void* __restrict__ w2,
                                             const int* __restrict__ flagp,
                                             const int* __restrict__ rp,
                                             const int* __restrict__ rank,
                                             unsigned* __restrict__ adj) {
    const int CB[9] = {0, 12500, 25000, 37500, 50000, 61250, 67500, 73750, 80000};
    const int cls = blockIdx.x & 7;
    const int lo = CB[cls], hi = CB[cls + 1];
    const int f = flagp[0];
    const int e0 = (blockIdx.x >> 3) * FCH;
    for (int i = threadIdx.x; i < FCH; i += 256) {
        int e = e0 + i;
        if (e >= E_ALL) return;
        int g;
        if (e < E_TIC) g = d0[e];
        else if (e < E_TIC + E_W) g = N_AC + d1[e - E_TIC];
        else g = N_AC + N_W + d2[e - E_TIC - E_W];
        if (g < lo || g >= hi) continue;
        int sn; float ew;
        if (e < E_TIC) { sn = s0[e]; ew = ldf(w0, e, f); }
        else if (e < E_TIC + E_W) { int le = e - E_TIC; sn = s1[le]; ew = ldf(w1, le, f); }
        else { int le = e - E_TIC - E_W; sn = s2[le]; ew = ldf(w2, le, f); }
        int pos = rp[g] + rank[e];
        adj[pos] = (unsigned)(sn & 0xFFFF) | ((unsigned)f2bf(ew) << 16);
    }
}

// ---------------- standalone wrappers ----------------
__global__ __launch_bounds__(256) void mgemm1(const void* __restrict__ X,
                                              const int* __restrict__ flagp,
                                              const ushort_t* __restrict__ WT,
                                              ushort_t* __restrict__ Zb,
                                              const float* __restrict__ alp,
                                              const float* __restrict__ arp,
                                              float* __restrict__ elo,
                                              float* __restrict__ ero) {
    dev_mgemm1(blockIdx.x, X, flagp[0], WT, Zb, alp, arp, elo, ero);
}

__global__ __launch_bounds__(256) void elr1(const void* __restrict__ X,
                                            const int* __restrict__ flagp,
                                            const float* __restrict__ q0,
                                            float* __restrict__ o0,
                                            int N, int D, int Hh) {
    dev_elr1(blockIdx.x, X, flagp ? flagp[0] : 0, q0, o0, N, D, Hh);
}

// ---------------- MFMA GEMM L2 fused over 3 etype segments ----------------
struct G2 {
    const ushort_t* Hb[3]; const ushort_t* WT[3]; ushort_t* Zc[3];
    const float* al[3]; const float* ar[3]; float* el[3]; float* er[3];
    int N[3]; int b1, b2;
};
__global__ __launch_bounds__(256) void mgemm2_all(G2 t) {
    int s, b;
    if (blockIdx.x < (unsigned)t.b1) { s = 0; b = blockIdx.x; }
    else if (blockIdx.x < (unsigned)t.b2) { s = 1; b = blockIdx.x - t.b1; }
    else { s = 2; b = blockIdx.x - t.b2; }
    const int w = threadIdx.x >> 6, l = threadIdx.x & 63;
    const int row0 = b * 64 + w * 16;
    if (row0 >= t.N[s]) return;
    const int lr = l & 15, lk = l >> 4;
    const ushort_t* ap = t.Hb[s] + (size_t)(row0 + lr) * 256 + lk * 8;
    const ushort_t* WT = t.WT[s];

    f32x4 acc[4] = {{0.f,0.f,0.f,0.f},{0.f,0.f,0.f,0.f},{0.f,0.f,0.f,0.f},{0.f,0.f,0.f,0.f}};
    #pragma unroll
    for (int ks = 0; ks < 8; ++ks) {
        bf16x8 a = *(const bf16x8*)(ap + ks * 32);
        #pragma unroll
        for (int nt = 0; nt < 4; ++nt) {
            bf16x8 bb = *(const bf16x8*)(WT + (size_t)(nt * 16 + lr) * 256 + ks * 32 + lk * 8);
            acc[nt] = __builtin_amdgcn_mfma_f32_16x16x32_bf16(a, bb, acc[nt], 0, 0, 0);
        }
    }
    ushort_t* Zc = t.Zc[s];
    #pragma unroll
    for (int nt = 0; nt < 4; ++nt)
        #pragma unroll
        for (int r = 0; r < 4; ++r)
            Zc[(size_t)(row0 + lk * 4 + r) * DOUT + nt * 16 + lr] = f2bf(acc[nt][r]);

    if (t.al[s]) {
        const float* alp = t.al[s];
        float a0 = alp[lr], a1 = alp[16 + lr], a2 = alp[32 + lr], a3 = alp[48 + lr];
        #pragma unroll
        for (int r = 0; r < 4; ++r) {
            float v = acc[0][r] * a0 + acc[1][r] * a1 + acc[2][r] * a2 + acc[3][r] * a3;
            v += __shfl_xor(v, 1, 64); v += __shfl_xor(v, 2, 64);
            v += __shfl_xor(v, 4, 64); v += __shfl_xor(v, 8, 64);
            if (lr == r) t.el[s][row0 + lk * 4 + r] = v;
        }
    }
    if (t.ar[s]) {
        const float* arp = t.ar[s];
        float a0 = arp[lr], a1 = arp[16 + lr], a2 = arp[32 + lr], a3 = arp[48 + lr];
        #pragma unroll
        for (int r = 0; r < 4; ++r) {
            float v = acc[0][r] * a0 + acc[1][r] * a1 + acc[2][r] * a2 + acc[3][r] * a3;
            v += __shfl_xor(v, 1, 64); v += __shfl_xor(v, 2, 64);
            v += __shfl_xor(v, 4, 64); v += __shfl_xor(v, 8, 64);
            if (lr == r) t.er[s][row0 + lk * 4 + r] = v;
        }
    }
}

// ---------------- fused CSR/ELL gather layer 2 over 3 segments ----------------
struct GA2 {
    const int* rp[3]; const int* degp; int gbase[3]; int ell;
    const ushort_t* zc[3]; const float* el[3]; const float* er[3];
    int N[3]; int b1, b2;
};
__global__ __launch_bounds__(256) void gat2_all(GA2 t, const unsigned* __restrict__ adj,
                                                const float* __restrict__ b2t,
                                                float* __restrict__ ACCw,
                                                float* __restrict__ ACCr,
                                                void* __restrict__ out,
                                                const int* __restrict__ flagp) {
    __shared__ float atl[4][CAP];
    __shared__ int   snl[4][CAP];
    int s, b;
    if (blockIdx.x < (unsigned)t.b1) { s = 0; b = blockIdx.x; }
    else if (blockIdx.x < (unsigned)t.b2) { s = 1; b = blockIdx.x - t.b1; }
    else { s = 2; b = blockIdx.x - t.b2; }
    const int w = threadIdx.x >> 6, lane = threadIdx.x & 63;
    const int n = b * 4 + w;
    if (n >= t.N[s]) return;
    const float* el = t.el[s];
    const ushort_t* zb = t.zc[s];
    int beg, deg;
    if (t.ell) {
        int g = t.gbase[s] + n;
        beg = g * ELLW;
        deg = t.degp[g];
        deg = deg < ELLW ? deg : ELLW;
    } else {
        const int* rp = t.rp[s];
        beg = rp[n];
        deg = rp[n + 1] - beg;
    }
    const float ern = t.er[s][n];

    float ssum = 0.f;
    for (int base = 0; base < deg; base += 64) {
        int i = base + lane;
        if (i < deg) {
            unsigned ae = adj[beg + i];
            int sn = ae & 0xFFFF;
            float x = lrelu_exp(el[sn] + ern);
            ssum += x;
            if (i < CAP) {
                atl[w][i] = x * bf2f((ushort_t)(ae >> 16));
                snl[w][i] = sn;
            }
        }
    }
    #pragma unroll
    for (int o = 32; o > 0; o >>= 1) ssum += __shfl_xor(ssum, o, 64);
    const float inv = 1.f / (ssum + 1e-9f);

    const int eoff = lane >> 4;
    const int c4 = (lane & 15) * 4;
    const int degc = deg < CAP ? deg : CAP;
    float a0 = 0.f, a1 = 0.f, a2 = 0.f, a3 = 0.f;
    #pragma unroll 2
    for (int i = 0; i < degc; i += 4) {
        int ii = i + eoff;
        int iic = ii < degc ? ii : degc - 1;
        float atv = ii < degc ? atl[w][iic] : 0.f;
        int sn = snl[w][iic];
        ushort4 zv = *(const ushort4*)(zb + (size_t)sn * DOUT + c4);
        a0 += bf2f(zv.x) * atv; a1 += bf2f(zv.y) * atv;
        a2 += bf2f(zv.z) * atv; a3 += bf2f(zv.w) * atv;
    }
    for (int i = CAP; i < deg; i += 4) {
        int ii = i + eoff;
        int iic = ii < deg ? ii : deg - 1;
        unsigned ae = adj[beg + iic];
        int sn = ae & 0xFFFF;
        float atv = lrelu_exp(el[sn] + ern) * bf2f((ushort_t)(ae >> 16));
        if (ii >= deg) atv = 0.f;
        ushort4 zv = *(const ushort4*)(zb + (size_t)sn * DOUT + c4);
        a0 += bf2f(zv.x) * atv; a1 += bf2f(zv.y) * atv;
        a2 += bf2f(zv.z) * atv; a3 += bf2f(zv.w) * atv;
    }
    a0 += __shfl_xor(a0, 16, 64); a0 += __shfl_xor(a0, 32, 64);
    a1 += __shfl_xor(a1, 16, 64); a1 += __shfl_xor(a1, 32, 64);
    a2 += __shfl_xor(a2, 16, 64); a2 += __shfl_xor(a2, 32, 64);
    a3 += __shfl_xor(a3, 16, 64); a3 += __shfl_xor(a3, 32, 64);
    a0 *= inv; a1 *= inv; a2 *= inv; a3 *= inv;

    if (lane < 16) {
        size_t o = (size_t)n * DOUT + c4;
        if (s == 0) {
            float v0 = a0 + b2t[c4], v1 = a1 + b2t[c4 + 1];
            float v2 = a2 + b2t[c4 + 2], v3 = a3 + b2t[c4 + 3];
            if (flagp[0]) { *(float4*)((float*)out + o) = make_float4(v0, v1, v2, v3); }
            else {
                ushort4 ov;
                ov.x = f2bf(v0); ov.y = f2bf(v1); ov.z = f2bf(v2); ov.w = f2bf(v3);
                *(ushort4*)((ushort_t*)out + o) = ov;
            }
        } else if (s == 1) {
            *(float4*)(ACCw + o) = make_float4(a0, a1, a2, a3);
        } else {
            *(float4*)(ACCr + o) = make_float4(a0, a1, a2, a3);
        }
    }
}

__global__ __launch_bounds__(256) void out_word(const float* __restrict__ aw,
                                                const float* __restrict__ bw,
                                                const float* __restrict__ ar_,
                                                const float* __restrict__ br,
                                                void* __restrict__ out,
                                                const int* __restrict__ flagp, int total) {
    int i = blockIdx.x * 256 + threadIdx.x;
    if (i >= total) return;
    int c = i & 63;
    float v = ((aw[i] + bw[c]) + (ar_[i] + br[c])) * 0.5f;
    size_t o = (size_t)N_AC * DOUT + i;
    if (flagp[0]) ((float*)out)[o] = v;
    else ((ushort_t*)out)[o] = f2bf(v);
}

// ---------------- host launch ----------------
extern "C" void kernel_launch(void* const* d_in, const int* in_sizes, int n_in,
                              void* d_out, int out_size, void* d_ws, size_t ws_size,
                              hipStream_t stream) {
    (void)in_sizes; (void)n_in; (void)out_size;

    const void* x_ac = d_in[0];
    const void* x_w  = d_in[1];
    const void* ew_tic = d_in[2];
    const void* ew_w   = d_in[3];
    const void* ew_rel = d_in[4];
    const int* src_tic = (const int*)d_in[29];
    const int* dst_tic = (const int*)d_in[30];
    const int* src_w   = (const int*)d_in[31];
    const int* dst_w   = (const int*)d_in[32];
    const int* src_rel = (const int*)d_in[33];
    const int* dst_rel = (const int*)d_in[34];

    float* ws = (float*)d_ws;
    int* FLAG = (int*)ws;

    float* PAR = ws + 16;
    const int o_W1t = 1000000, o_W1w = 1032768, o_W1r = 1065536;
    const int o_W2t = 1098304, o_W2w = 1114688, o_W2r = 1131072;
    const int o_al1t = 1147456, o_ar1t = 1147712, o_al1w = 1147968, o_ar1w = 1148224,
              o_al1r = 1148480, o_ar1r = 1148736;
    const int o_b1t = 1148992, o_b1w = 1149248, o_b1r = 1149504;
    const int o_al2t = 1149760, o_ar2t = 1149824, o_al2w = 1149888, o_ar2w = 1149952,
              o_al2r = 1150016, o_ar2r = 1150080;
    const int o_b2t = 1150144, o_b2w = 1150208, o_b2r = 1150272;
    const int o_qer1r = 1150400, o_qer2r = 1150912;

    float* EB   = ws + 1160016;
    float* ELt  = EB;
    float* ERt  = EB + 160000;
    float* ELw  = EB + 320000;
    float* ERw  = EB + 400000;
    float* ELr  = EB + 480000;
    float* ERr  = EB + 640000;
    float* E2tl = EB + 720000;
    float* E2tr = EB + 760000;
    float* E2wl = EB + 800000;
    float* E2wr = EB + 820000;
    float* E2rl = EB + 840000;
    float* E2rr = EB + 880000;

    const size_t NEED_A = 27813744ull * 4ull;   // 111.3 MB
    const bool pathA = ws_size >= NEED_A;

    // ---- P0 (shared) ----
    detect_dtype<<<1, 256, 0, stream>>>((const ushort_t*)x_ac, FLAG);

    CvtTab ct;
    const int srcIdx[24] = {5,6,7,8, 9,10,11,12, 13,14,15,16,
                            17,18,19,20, 21,22,23,24, 25,26,27,28};
    const int sizes[24] = {32768,256,256,256, 32768,256,256,256, 32768,256,256,256,
                           16384,64,64,64, 16384,64,64,64, 16384,64,64,64};
    const int offs[24] = {o_W1t,o_al1t,o_ar1t,o_b1t, o_W1w,o_al1w,o_ar1w,o_b1w,
                          o_W1r,o_al1r,o_ar1r,o_b1r,
                          o_W2t,o_al2t,o_ar2t,o_b2t, o_W2w,o_al2w,o_ar2w,o_b2w,
                          o_W2r,o_al2r,o_ar2r,o_b2r};
    for (int i = 0; i < 24; ++i) { ct.src[i] = d_in[srcIdx[i]]; ct.n[i] = sizes[i]; ct.off[i] = offs[i]; }
    cvt_inputs<<<24 * 8, 256, 0, stream>>>(ct, PAR, FLAG);

    QTab qt;
    qt.woff[0] = o_W1r; qt.aoff[0] = o_ar1r; qt.qoff[0] = o_qer1r; qt.K[0] = 128; qt.Hh[0] = 4;
    qt.woff[1] = o_W2r; qt.aoff[1] = o_ar2r; qt.qoff[1] = o_qer2r; qt.K[1] = 256; qt.Hh[1] = 1;
    make_q<<<2, 256, 0, stream>>>(qt, PAR);

    if (pathA) {
        ushort_t* Z_tic = (ushort_t*)(ws + 2060016);
        ushort_t* Z_w   = (ushort_t*)(ws + 7180016);
        ushort_t* Z_rel = (ushort_t*)(ws + 9740016);
        float* ACCw = ws + 9740016;                    // aliases Z_rel (dead after gat1<2>)
        float* ACCr = ws + 11020016;
        ushort_t* Hac = (ushort_t*)(ws + 14860016);
        ushort_t* Hw  = (ushort_t*)(ws + 19980016);
        ushort_t* WT  = (ushort_t*)(ws + 22540016);
        int* cntA = (int*)(ws + 22613744);             // N_ALL
        unsigned* adjA = (unsigned*)(ws + 22693744);   // N_ALL*ELLW -> ends 27813744
        ushort_t* Zc_tic = Z_tic;
        ushort_t* Zc_w   = Z_tic + 2560000;
        ushort_t* Zc_r   = Z_tic + 3840000;
        const int t_W1t = 0, t_W1w = 32768, t_W1r = 65536,
                  t_W2t = 98304, t_W2w = 114688, t_W2r = 131072;

        PTab pt;
        const int pw[6] = {o_W1t, o_W1w, o_W1r, o_W2t, o_W2w, o_W2r};
        const int ptf[6] = {t_W1t, t_W1w, t_W1r, t_W2t, t_W2w, t_W2r};
        for (int i = 0; i < 6; ++i) {
            pt.woff[i] = pw[i]; pt.toff[i] = ptf[i];
            pt.Klog[i] = (i < 3) ? 7 : 8; pt.N[i] = (i < 3) ? 256 : 64;
        }
        pack_wt<<<6 * 16, 256, 0, stream>>>(pt, PAR, WT);

        hipMemsetAsync(cntA, 0, N_ALL * 4, stream);

        // ---- fused front-end: range-restricted class fill || 3x mgemm1 || elr1 ----
        FA fa;
        fa.s0 = src_tic; fa.d0 = dst_tic; fa.w0 = ew_tic;
        fa.s1 = src_w;   fa.d1 = dst_w;   fa.w1 = ew_w;
        fa.s2 = src_rel; fa.d2 = dst_rel; fa.w2 = ew_rel;
        fa.flagp = FLAG; fa.cnt = cntA; fa.adj = adjA;
        fa.x_ac = x_ac; fa.x_w = x_w;
        fa.WTt = WT + t_W1t; fa.WTw = WT + t_W1w; fa.WTr = WT + t_W1r;
        fa.Zt = Z_tic; fa.Zw = Z_w; fa.Zr = Z_rel;
        fa.al1t = PAR + o_al1t; fa.ar1t = PAR + o_ar1t;
        fa.al1w = PAR + o_al1w; fa.ar1w = PAR + o_ar1w;
        fa.al1r = PAR + o_al1r;
        fa.ELt = ELt; fa.ERt = ERt; fa.ELw = ELw; fa.ERw = ERw;
        fa.ELr = ELr; fa.ERr = ERr;
        fa.qer1r = PAR + o_qer1r;
        fa.c0 = FILL_BLOCKS;                         // 886 range-restricted fill blocks
        fa.c1 = fa.c0 + N_AC / 16;
        fa.c2 = fa.c1 + N_W / 16;
        fa.c3 = fa.c2 + N_AC / 16;
        const unsigned ctot = fa.c3 + N_W / 4;
        fused_a<<<ctot, 256, 0, stream>>>(fa);

        // ---- layer-1 gathers: tic+w fused, then rel (+E2rr epilogue) ----
        GT gt;
        gt.degp = cntA; gt.adj = adjA;
        gt.Zt = Z_tic; gt.Zw = Z_w;
        gt.ELt = ELt; gt.ERt = ERt; gt.ELw = ELw; gt.ERw = ERw;
        gt.b1t = PAR + o_b1t; gt.b1w = PAR + o_b1w;
        gt.Hac = Hac; gt.Hw = Hw;
        gt.b1 = N_AC / 4;
        gat1_tw<<<N_AC / 4 + N_W / 4, 256, 0, stream>>>(gt);

        gat1<2><<<N_W / 4, 256, 0, stream>>>(nullptr, cntA, N_AC + N_W, 1, adjA, Z_rel,
                                             ELr, ERr, PAR + o_b1r, Hw, N_W,
                                             PAR + o_qer2r, E2rr);

        // ---- layer 2 ----
        G2 g2;
        g2.Hb[0] = Hac; g2.Hb[1] = Hw; g2.Hb[2] = Hac;
        g2.WT[0] = WT + t_W2t; g2.WT[1] = WT + t_W2w; g2.WT[2] = WT + t_W2r;
        g2.Zc[0] = Zc_tic; g2.Zc[1] = Zc_w; g2.Zc[2] = Zc_r;
        g2.al[0] = PAR + o_al2t; g2.al[1] = PAR + o_al2w; g2.al[2] = PAR + o_al2r;
        g2.ar[0] = PAR + o_ar2t; g2.ar[1] = PAR + o_ar2w; g2.ar[2] = nullptr;
        g2.el[0] = E2tl; g2.el[1] = E2wl; g2.el[2] = E2rl;
        g2.er[0] = E2tr; g2.er[1] = E2wr; g2.er[2] = nullptr;
        g2.N[0] = N_AC; g2.N[1] = N_W; g2.N[2] = N_AC;
        const int nb0 = (N_AC + 63) / 64, nb1 = (N_W + 63) / 64, nb2 = (N_AC + 63) / 64;
        g2.b1 = nb0; g2.b2 = nb0 + nb1;
        mgemm2_all<<<nb0 + nb1 + nb2, 256, 0, stream>>>(g2);

        GA2 ga;
        ga.rp[0] = ga.rp[1] = ga.rp[2] = nullptr;
        ga.degp = cntA; ga.ell = 1;
        ga.gbase[0] = 0; ga.gbase[1] = N_AC; ga.gbase[2] = N_AC + N_W;
        ga.zc[0] = Zc_tic; ga.zc[1] = Zc_w; ga.zc[2] = Zc_r;
        ga.el[0] = E2tl; ga.el[1] = E2wl; ga.el[2] = E2rl;
        ga.er[0] = E2tr; ga.er[1] = E2wr; ga.er[2] = E2rr;
        ga.N[0] = N_AC; ga.N[1] = N_W; ga.N[2] = N_W;
        const int gb0 = N_AC / 4, gb1 = N_W / 4, gb2 = N_W / 4;
        ga.b1 = gb0; ga.b2 = gb0 + gb1;
        gat2_all<<<gb0 + gb1 + gb2, 256, 0, stream>>>(ga, adjA, PAR + o_b2t, ACCw, ACCr, d_out, FLAG);

        out_word<<<(N_W * DOUT) / 256, 256, 0, stream>>>(ACCw, PAR + o_b2w, ACCr, PAR + o_b2r,
                                                         d_out, FLAG, N_W * DOUT);
    } else {
        // ---------- PATH B: round-12 proven flow ----------
        float* ACC = ws + 2060016;
        ushort_t* Zb  = (ushort_t*)(ws + 3340016);
        ushort_t* Hac = (ushort_t*)(ws + 8460016);
        ushort_t* Hw  = (ushort_t*)(ws + 13580016);
        ushort_t* WT  = (ushort_t*)(ws + 16140016);
        const int t_W1t = 0, t_W1w = 32768, t_W1r = 65536,
                  t_W2t = 98304, t_W2w = 114688, t_W2r = 131072;
        int* IB = (int*)(ws + 16213760);
        int* rp   = IB;
        int* cnt  = IB + 80064;
        int* bsum = IB + 160128;
        unsigned* adj = (unsigned*)(IB + 160704);
        int* rank = IB + 1160704;
        float* ACCr = ws + 18374464;
        ushort_t* Zc_tic = Zb;
        ushort_t* Zc_w   = Zb + 2560000;
        ushort_t* Zc_r   = Zb + 3840000;

        PTab pt;
        const int pw[6] = {o_W1t, o_W1w, o_W1r, o_W2t, o_W2w, o_W2r};
        const int ptf[6] = {t_W1t, t_W1w, t_W1r, t_W2t, t_W2w, t_W2r};
        for (int i = 0; i < 6; ++i) {
            pt.woff[i] = pw[i]; pt.toff[i] = ptf[i];
            pt.Klog[i] = (i < 3) ? 7 : 8; pt.N[i] = (i < 3) ? 256 : 64;
        }
        pack_wt<<<6 * 16, 256, 0, stream>>>(pt, PAR, WT);

        {
            const int B = (N_ALL + 255) / 256;
            hipMemsetAsync(cnt, 0, N_ALL * 4, stream);
            count3<<<(E_ALL + 255) / 256, 256, 0, stream>>>(dst_tic, dst_w, dst_rel, cnt, rank);
            scan_bsum<<<B, 256, 0, stream>>>(cnt, bsum, N_ALL);
            scan_top<<<1, 512, 0, stream>>>(bsum, B);
            scan_out<<<B, 256, 0, stream>>>(cnt, bsum, rp, N_ALL);
            fill3<<<8 * ((E_ALL + FCH - 1) / FCH), 256, 0, stream>>>(
                src_tic, dst_tic, ew_tic, src_w, dst_w, ew_w, src_rel, dst_rel, ew_rel,
                FLAG, rp, rank, adj);
        }
        const int* rp_tic = rp;
        const int* rp_w   = rp + N_AC;
        const int* rp_rel = rp + N_AC + N_W;

        elr1<<<N_W / 4, 256, 0, stream>>>(x_w, FLAG, PAR + o_qer1r, ERr, N_W, 128, 4);

        mgemm1<<<N_AC / 16, 256, 0, stream>>>(x_ac, FLAG, WT + t_W1t, Zb,
                                              PAR + o_al1t, PAR + o_ar1t, ELt, ERt);
        gat1<0><<<N_AC / 4, 256, 0, stream>>>(rp_tic, nullptr, 0, 0, adj, Zb,
                                              ELt, ERt, PAR + o_b1t, Hac, N_AC, nullptr, nullptr);

        mgemm1<<<N_W / 16, 256, 0, stream>>>(x_w, FLAG, WT + t_W1w, Zb,
                                             PAR + o_al1w, PAR + o_ar1w, ELw, ERw);
        gat1<1><<<N_W / 4, 256, 0, stream>>>(rp_w, nullptr, 0, 0, adj, Zb,
                                             ELw, ERw, PAR + o_b1w, Hw, N_W, nullptr, nullptr);

        mgemm1<<<N_AC / 16, 256, 0, stream>>>(x_ac, FLAG, WT + t_W1r, Zb,
                                              PAR + o_al1r, nullptr, ELr, nullptr);
        gat1<2><<<N_W / 4, 256, 0, stream>>>(rp_rel, nullptr, 0, 0, adj, Zb,
                                             ELr, ERr, PAR + o_b1r, Hw, N_W,
                                             PAR + o_qer2r, E2rr);

        G2 g2;
        g2.Hb[0] = Hac; g2.Hb[1] = Hw; g2.Hb[2] = Hac;
        g2.WT[0] = WT + t_W2t; g2.WT[1] = WT + t_W2w; g2.WT[2] = WT + t_W2r;
        g2.Zc[0] = Zc_tic; g2.Zc[1] = Zc_w; g2.Zc[2] = Zc_r;
        g2.al[0] = PAR + o_al2t; g2.al[1] = PAR + o_al2w; g2.al[2] = PAR + o_al2r;
        g2.ar[0] = PAR + o_ar2t; g2.ar[1] = PAR + o_ar2w; g2.ar[2] = nullptr;
        g2.el[0] = E2tl; g2.el[1] = E2wl; g2.el[2] = E2rl;
        g2.er[0] = E2tr; g2.er[1] = E2wr; g2.er[2] = nullptr;
        g2.N[0] = N_AC; g2.N[1] = N_W; g2.N[2] = N_AC;
        const int nb0 = (N_AC + 63) / 64, nb1 = (N_W + 63) / 64, nb2 = (N_AC + 63) / 64;
        g2.b1 = nb0; g2.b2 = nb0 + nb1;
        mgemm2_all<<<nb0 + nb1 + nb2, 256, 0, stream>>>(g2);

        GA2 ga;
        ga.rp[0] = rp_tic; ga.rp[1] = rp_w; ga.rp[2] = rp_rel;
        ga.degp = nullptr; ga.ell = 0;
        ga.gbase[0] = ga.gbase[1] = ga.gbase[2] = 0;
        ga.zc[0] = Zc_tic; ga.zc[1] = Zc_w; ga.zc[2] = Zc_r;
        ga.el[0] = E2tl; ga.el[1] = E2wl; ga.el[2] = E2rl;
        ga.er[0] = E2tr; ga.er[1] = E2wr; ga.er[2] = E2rr;
        ga.N[0] = N_AC; ga.N[1] = N_W; ga.N[2] = N_W;
        const int gb0 = N_AC / 4, gb1 = N_W / 4, gb2 = N_W / 4;
        ga.b1 = gb0; ga.b2 = gb0 + gb1;
        gat2_all<<<gb0 + gb1 + gb2, 256, 0, stream>>>(ga, adj, PAR + o_b2t, ACC, ACCr, d_out, FLAG);

        out_word<<<(N_W * DOUT) / 256, 256, 0, stream>>>(ACC, PAR + o_b2w, ACCr, PAR + o_b2r,
                                                         d_out, FLAG, N_W * DOUT);
    }
}